// Round 6
// baseline (1334.832 us; speedup 1.0000x reference)
//
#include <hip/hip_runtime.h>
#include <hip/hip_fp16.h>
#include <math.h>

#define N_NODES 50000
#define N_EDGES 800000
#define MPAD 50048            // 391 * 128, so GEMM needs no M bounds checks
#define NBANDS (MPAD / 128)   // 391 row bands
#define KPHYS 1024            // A2 physical row width: [hi(512) | lo(512)]
#define KB 1024               // B2T physical row width: [hi(512) | lo(512)]
#define NOUTER 16             // 16 outer iters x 32 cols = 512 K
#define SCANB ((N_NODES + 255) / 256)  // 196 scan blocks

// ---------------- bf16 helpers ----------------

__device__ __forceinline__ unsigned short bf16_rn(float f) {
    unsigned u = __float_as_uint(f);
    u += 0x7FFFu + ((u >> 16) & 1u);  // round-to-nearest-even
    return (unsigned short)(u >> 16);
}
__device__ __forceinline__ float bf16_f32(unsigned short h) {
    return __uint_as_float(((unsigned)h) << 16);
}

typedef __attribute__((ext_vector_type(2))) float f2v;

__device__ __forceinline__ float2 ntload2(const float* p) {
    f2v v = __builtin_nontemporal_load((const f2v*)p);
    return make_float2(v[0], v[1]);
}

// CSR nt-load: the edge stream is read once per XCD -> keep it out of L2 LRU
__device__ __forceinline__ int2 ntload_edge(const int2* p) {
    long long raw = __builtin_nontemporal_load((const long long*)p);
    return make_int2((int)(raw & 0xffffffffLL), (int)(raw >> 32));
}

// ---------------- degree / CSR build ----------------

__global__ void zero_int_kernel(int* __restrict__ p, int n) {
    int i = blockIdx.x * blockDim.x + threadIdx.x;
    if (i < n) p[i] = 0;
}

__global__ void count_deg_kernel(const int* __restrict__ dst, int* __restrict__ deg) {
    int e = blockIdx.x * blockDim.x + threadIdx.x;
    if (e < N_EDGES) atomicAdd(&deg[dst[e]], 1);
}

__global__ void dinv_kernel(const int* __restrict__ deg, float* __restrict__ dinv) {
    int i = blockIdx.x * blockDim.x + threadIdx.x;
    if (i < N_NODES) dinv[i] = rsqrtf((float)deg[i] + 1.0f);  // +1 self-loop
}

// 3-kernel scan (multi-block)
__global__ __launch_bounds__(256) void scan1_kernel(const int* __restrict__ deg,
                                                    int* __restrict__ local_scan,
                                                    int* __restrict__ partials) {
    __shared__ int sm[256];
    int b = blockIdx.x, t = threadIdx.x;
    int i = b * 256 + t;
    int v = (i < N_NODES) ? deg[i] : 0;
    sm[t] = v;
    __syncthreads();
    for (int off = 1; off < 256; off <<= 1) {
        int x = (t >= off) ? sm[t - off] : 0;
        __syncthreads();
        sm[t] += x;
        __syncthreads();
    }
    if (i < N_NODES) local_scan[i] = sm[t];
    if (t == 255) partials[b] = sm[255];
}

__global__ __launch_bounds__(256) void scan2_kernel(int* __restrict__ partials) {
    __shared__ int sm[256];
    int t = threadIdx.x;
    sm[t] = (t < SCANB) ? partials[t] : 0;
    __syncthreads();
    for (int off = 1; off < 256; off <<= 1) {
        int x = (t >= off) ? sm[t - off] : 0;
        __syncthreads();
        sm[t] += x;
        __syncthreads();
    }
    if (t < SCANB) partials[t] = (t == 0) ? 0 : sm[t - 1];  // exclusive
}

__global__ __launch_bounds__(256) void scan3_kernel(const int* __restrict__ deg,
                                                    const int* __restrict__ local_scan,
                                                    const int* __restrict__ partials,
                                                    int* __restrict__ offsets,
                                                    int* __restrict__ cursor) {
    int i = blockIdx.x * 256 + threadIdx.x;
    if (i == 0) offsets[0] = 0;
    if (i < N_NODES) {
        int incl = local_scan[i] + partials[blockIdx.x];
        offsets[i + 1] = incl;
        cursor[i] = incl - deg[i];
    }
}

// packed CSR entry: {src, weight-as-bits} -> one 8B load per edge
__global__ void fill_csr_kernel(const int* __restrict__ src, const int* __restrict__ dst,
                                int* __restrict__ cursor, int2* __restrict__ csr_sw,
                                const float* __restrict__ dinv) {
    int e = blockIdx.x * blockDim.x + threadIdx.x;
    if (e < N_EDGES) {
        int s = src[e], d = dst[e];
        int p = atomicAdd(&cursor[d], 1);
        csr_sw[p] = make_int2(s, __float_as_int(dinv[s] * dinv[d]));
    }
}

// ---------------- split-bf16 MFMA GEMM (fp16 hi/lo output) ----------------
// R4: XCD-affine block decode (b&7 = XCD, all col-blocks of a row band share
// the XCD so the A band is fetched once into one L2).

typedef __attribute__((ext_vector_type(8))) short bf16x8;
typedef __attribute__((ext_vector_type(4))) float floatx4;

#define GLL16(g, l)                                                                   \
    __builtin_amdgcn_global_load_lds((__attribute__((address_space(1))) const void*)(g), \
                                     (__attribute__((address_space(3))) void*)(l), 16, 0, 0)

__global__ __launch_bounds__(256) void gemm_split_bt(const unsigned short* __restrict__ A2,
                                                     const unsigned short* __restrict__ B2T,
                                                     __half* __restrict__ Chi,
                                                     __half* __restrict__ Clo, int N,
                                                     int cshift) {
    // XCD-affine decode (cshift = log2(ncol_blocks): 2 for N=512, 1 for N=256)
    const int b = blockIdx.x;
    const int xcd = b & 7;
    const int q = b >> 3;
    const int cb = q & ((1 << cshift) - 1);
    const int bh = q >> cshift;
    const int r = bh * 8 + xcd;
    if (r >= NBANDS) return;
    const int row0 = r * 128;
    const int col0 = cb * 128;

    // [buf][hi/lo] 128x32 chunks, double-buffered: 64 KiB total
    __shared__ unsigned short As[2][2][128 * 32];
    __shared__ unsigned short Bs[2][2][128 * 32];

    const int t = threadIdx.x;
    const int lane = t & 63;
    const int quad = lane >> 4;
    const int l15 = lane & 15;
    const int w = t >> 6;
    const int wm = w & 1, wn = w >> 1;

    floatx4 acc[4][4];
#pragma unroll
    for (int i = 0; i < 4; i++)
#pragma unroll
        for (int j = 0; j < 4; j++) acc[i][j] = (floatx4){0.f, 0.f, 0.f, 0.f};

    // coalesced staging with XOR-swizzled k-chunk
    const int sr = t >> 2;
    const int sk = ((t & 3) ^ ((t >> 3) & 3)) * 8;
    const unsigned short* Arow0 = A2 + (size_t)(row0 + sr) * KPHYS + sk;
    const unsigned short* Arow1 = Arow0 + (size_t)64 * KPHYS;
    const unsigned short* Brow0 = B2T + (size_t)(col0 + sr) * KB + sk;
    const unsigned short* Brow1 = Brow0 + (size_t)64 * KB;

    // fragment-read swizzle: chunk column = quad ^ ((l15>>1)&3)
    const int fcol = (quad ^ ((l15 >> 1) & 3)) * 8;

#define STAGE(buf, k32)                                            \
    do {                                                           \
        GLL16(Arow0 + (k32), As[buf][0] + t * 8);                  \
        GLL16(Arow1 + (k32), As[buf][0] + 2048 + t * 8);           \
        GLL16(Arow0 + 512 + (k32), As[buf][1] + t * 8);            \
        GLL16(Arow1 + 512 + (k32), As[buf][1] + 2048 + t * 8);     \
        GLL16(Brow0 + (k32), Bs[buf][0] + t * 8);                  \
        GLL16(Brow1 + (k32), Bs[buf][0] + 2048 + t * 8);           \
        GLL16(Brow0 + 512 + (k32), Bs[buf][1] + t * 8);            \
        GLL16(Brow1 + 512 + (k32), Bs[buf][1] + 2048 + t * 8);     \
    } while (0)

    // prologue: stage chunk 0 into buffer 0
    STAGE(0, 0);

    for (int it = 0; it < NOUTER; it++) {
        const int cur = it & 1;
        __syncthreads();  // drains prefetch into cur; all reads of cur^1 done
        if (it + 1 < NOUTER) STAGE(cur ^ 1, (it + 1) * 32);

        bf16x8 afh[4], afl[4], bfh[4], bfl[4];
#pragma unroll
        for (int mt = 0; mt < 4; mt++) {
            const int ro = (wm * 64 + mt * 16 + l15) * 32 + fcol;
            afh[mt] = *(const bf16x8*)(As[cur][0] + ro);
            afl[mt] = *(const bf16x8*)(As[cur][1] + ro);
        }
#pragma unroll
        for (int nt = 0; nt < 4; nt++) {
            const int ro = (wn * 64 + nt * 16 + l15) * 32 + fcol;
            bfh[nt] = *(const bf16x8*)(Bs[cur][0] + ro);
            bfl[nt] = *(const bf16x8*)(Bs[cur][1] + ro);
        }
        // pass 1: hi*hi
#pragma unroll
        for (int mt = 0; mt < 4; mt++)
#pragma unroll
            for (int nt = 0; nt < 4; nt++)
                acc[mt][nt] = __builtin_amdgcn_mfma_f32_16x16x32_bf16(afh[mt], bfh[nt], acc[mt][nt], 0, 0, 0);
        // pass 2: lo*hi
#pragma unroll
        for (int mt = 0; mt < 4; mt++)
#pragma unroll
            for (int nt = 0; nt < 4; nt++)
                acc[mt][nt] = __builtin_amdgcn_mfma_f32_16x16x32_bf16(afl[mt], bfh[nt], acc[mt][nt], 0, 0, 0);
        // pass 3: hi*lo
#pragma unroll
        for (int mt = 0; mt < 4; mt++)
#pragma unroll
            for (int nt = 0; nt < 4; nt++)
                acc[mt][nt] = __builtin_amdgcn_mfma_f32_16x16x32_bf16(afh[mt], bfl[nt], acc[mt][nt], 0, 0, 0);
    }
#undef STAGE

#pragma unroll
    for (int mt = 0; mt < 4; mt++) {
#pragma unroll
        for (int rr = 0; rr < 4; rr++) {
            int row = row0 + wm * 64 + mt * 16 + quad * 4 + rr;
            __half* Cph = Chi + (size_t)row * N + col0 + wn * 64 + l15;
            __half* Cpl = Clo + (size_t)row * N + col0 + wn * 64 + l15;
#pragma unroll
            for (int nt = 0; nt < 4; nt++) {
                float a = acc[mt][nt][rr];
                __half hi = __float2half(a);
                __half lo = __float2half(a - __half2float(hi));
                Cph[nt * 16] = hi;
                Cpl[nt * 16] = lo;
            }
        }
    }
}

// ---------------- weight split (W [K x N] fp32 -> B2T [N x KB] bf16) ----------------

__global__ void wsplit_kernel(const float* __restrict__ W, unsigned short* __restrict__ B2T, int N) {
    int idx = blockIdx.x * blockDim.x + threadIdx.x;
    if (idx >= 512 * N) return;
    int k = idx / N, n = idx % N;
    float v = W[(size_t)k * N + n];
    unsigned short hi = bf16_rn(v);
    unsigned short lo = bf16_rn(v - bf16_f32(hi));
    unsigned short* row = B2T + (size_t)n * KB;
    row[k] = hi;
    row[512 + k] = lo;
}

// ---------------- x split (fp32 [N_NODES x 512] -> A2 [MPAD x KPHYS]) ----------------

__global__ __launch_bounds__(256) void split_x_kernel(const float* __restrict__ x,
                                                      unsigned short* __restrict__ A2) {
    int m = blockIdx.x;
    int ch = threadIdx.x * 2;
    unsigned short* arow = A2 + (size_t)m * KPHYS;
    float vx = 0.f, vy = 0.f;
    if (m < N_NODES) {
        float2 v = ntload2(x + (size_t)m * 512 + ch);  // x read exactly once
        vx = v.x;
        vy = v.y;
    }
    unsigned short hx = bf16_rn(vx), hy = bf16_rn(vy);
    arow[ch] = hx;
    arow[ch + 1] = hy;
    arow[512 + ch] = bf16_rn(vx - bf16_f32(hx));
    arow[512 + ch + 1] = bf16_rn(vy - bf16_f32(hy));
}

// ---------------- aggregation ----------------

__device__ __forceinline__ float gelu_tanh(float x) {
    float x3 = x * x * x;
    float inner = 0.7978845608028654f * (x + 0.044715f * x3);
    return 0.5f * x * (1.0f + tanhf(inner));
}

// R5: channel-sliced, XCD-affine aggregation.
// slice = blockIdx&7 -> XCD (round-robin dispatch); slice owns 64 channels.
// Per-XCD gather working set shrinks 51MB -> 6.4MB (its Chi column-slice), so
// the 16x in-degree reuse hits L2 instead of missing to the fabric. Each Chi/
// Clo byte is fetched by exactly ONE XCD (compulsory ~102MB vs R4's 430MB).
// Wave = 1 node; lane-half h handles edges p0+2j+h; ch/lane = 2 (dword gather).
__global__ __launch_bounds__(256) void aggregate_split_kernel(
    const __half* __restrict__ Chi, const __half* __restrict__ Clo,
    const int* __restrict__ offsets, const int2* __restrict__ csr_sw,
    const float* __restrict__ dinv,
    const float* __restrict__ bias, unsigned short* __restrict__ A2) {
    const int b = blockIdx.x;
    const int slice = b & 7;          // XCD-affine channel slice
    const int g = b >> 3;
    const int t = threadIdx.x;
    const int node = __builtin_amdgcn_readfirstlane(g * 4 + (t >> 6));
    const int lane = t & 63;
    const int half = lane >> 5;
    const int ch = slice * 64 + (lane & 31) * 2;

    unsigned short* arow = A2 + (size_t)node * KPHYS;
    if (node >= N_NODES) {  // zero-fill pad rows (this slice's chunks)
        if (half == 0) *(unsigned*)(arow + ch) = 0u;
        else *(unsigned*)(arow + 512 + ch) = 0u;
        return;
    }

    const int p0 = offsets[node], p1 = offsets[node + 1];
    const int nedge = p1 - p0;
    float a0 = 0.f, a1 = 0.f;

    const int nfull = nedge & ~7;  // 4 edges per half per iteration
    int q = half;
    for (; q < nfull; q += 8) {
        int2 e0 = ntload_edge(csr_sw + p0 + q);
        int2 e1 = ntload_edge(csr_sw + p0 + q + 2);
        int2 e2 = ntload_edge(csr_sw + p0 + q + 4);
        int2 e3 = ntload_edge(csr_sw + p0 + q + 6);
        __half2 v0 = *(const __half2*)(Chi + (size_t)e0.x * 512 + ch);
        __half2 v1 = *(const __half2*)(Chi + (size_t)e1.x * 512 + ch);
        __half2 v2 = *(const __half2*)(Chi + (size_t)e2.x * 512 + ch);
        __half2 v3 = *(const __half2*)(Chi + (size_t)e3.x * 512 + ch);
        float2 c0 = __half22float2(v0), c1 = __half22float2(v1);
        float2 c2 = __half22float2(v2), c3 = __half22float2(v3);
        float w0 = __int_as_float(e0.y), w1 = __int_as_float(e1.y);
        float w2 = __int_as_float(e2.y), w3 = __int_as_float(e3.y);
        a0 += w0 * c0.x + w1 * c1.x + w2 * c2.x + w3 * c3.x;
        a1 += w0 * c0.y + w1 * c1.y + w2 * c2.y + w3 * c3.y;
    }
    for (; q < nedge; q += 2) {
        int2 e = ntload_edge(csr_sw + p0 + q);
        __half2 v = *(const __half2*)(Chi + (size_t)e.x * 512 + ch);
        float2 c = __half22float2(v);
        float wg = __int_as_float(e.y);
        a0 += wg * c.x;
        a1 += wg * c.y;
    }

    // combine the two lane-halves (both end with the full sum)
    a0 += __shfl_xor(a0, 32);
    a1 += __shfl_xor(a1, 32);

    float di = dinv[node];
    float wself = di * di;
    __half2 vh = *(const __half2*)(Chi + (size_t)node * 512 + ch);
    __half2 vl = *(const __half2*)(Clo + (size_t)node * 512 + ch);
    float2 sh = __half22float2(vh), sl = __half22float2(vl);
    float2 bv = *(const float2*)(bias + ch);
    float r0 = gelu_tanh(a0 + wself * (sh.x + sl.x) + bv.x);
    float r1 = gelu_tanh(a1 + wself * (sh.y + sl.y) + bv.y);

    unsigned short h0 = bf16_rn(r0), h1 = bf16_rn(r1);
    unsigned short l0 = bf16_rn(r0 - bf16_f32(h0)), l1 = bf16_rn(r1 - bf16_f32(h1));
    if (half == 0) {
        *(unsigned*)(arow + ch) = (unsigned)h0 | ((unsigned)h1 << 16);
    } else {
        *(unsigned*)(arow + 512 + ch) = (unsigned)l0 | ((unsigned)l1 << 16);
    }
}

// Final agg, channel-sliced: 8 slices x 32 ch, slice = b&7 (3.2MB/XCD working
// set -> fits L2). Wave = 1 node; 4 edge-groups of 16 lanes; 2 ch per lane.
__global__ __launch_bounds__(256) void aggregate_final_kernel(
    const __half* __restrict__ Chi, const __half* __restrict__ Clo,
    const int* __restrict__ offsets, const int2* __restrict__ csr_sw,
    const float* __restrict__ dinv,
    const float* __restrict__ bias, float* __restrict__ out) {
    const int b = blockIdx.x;
    const int slice = b & 7;
    const int g = b >> 3;
    const int t = threadIdx.x;
    const int node = __builtin_amdgcn_readfirstlane(g * 4 + (t >> 6));
    if (node >= N_NODES) return;
    const int lane = t & 63;
    const int grp = lane >> 4;
    const int ch = slice * 32 + (lane & 15) * 2;

    const int p0 = offsets[node], p1 = offsets[node + 1];
    const int nedge = p1 - p0;
    float a0 = 0.f, a1 = 0.f;

    const int nfull = nedge & ~7;  // 2 edges per group per iteration
    int q = grp;
    for (; q < nfull; q += 8) {
        int2 e0 = ntload_edge(csr_sw + p0 + q);
        int2 e1 = ntload_edge(csr_sw + p0 + q + 4);
        __half2 v0 = *(const __half2*)(Chi + (size_t)e0.x * 256 + ch);
        __half2 v1 = *(const __half2*)(Chi + (size_t)e1.x * 256 + ch);
        float2 c0 = __half22float2(v0), c1 = __half22float2(v1);
        float w0 = __int_as_float(e0.y), w1 = __int_as_float(e1.y);
        a0 += w0 * c0.x + w1 * c1.x;
        a1 += w0 * c0.y + w1 * c1.y;
    }
    for (; q < nedge; q += 4) {
        int2 e = ntload_edge(csr_sw + p0 + q);
        __half2 v = *(const __half2*)(Chi + (size_t)e.x * 256 + ch);
        float2 c = __half22float2(v);
        float wg = __int_as_float(e.y);
        a0 += wg * c.x;
        a1 += wg * c.y;
    }

    // combine the four 16-lane groups
    a0 += __shfl_xor(a0, 16);
    a1 += __shfl_xor(a1, 16);
    a0 += __shfl_xor(a0, 32);
    a1 += __shfl_xor(a1, 32);

    float di = dinv[node];
    float wself = di * di;
    __half2 vh = *(const __half2*)(Chi + (size_t)node * 256 + ch);
    __half2 vl = *(const __half2*)(Clo + (size_t)node * 256 + ch);
    float2 sh = __half22float2(vh), sl = __half22float2(vl);
    float2 bv = *(const float2*)(bias + ch);
    if (lane < 16) {
        float2 o = make_float2(a0 + wself * (sh.x + sl.x) + bv.x,
                               a1 + wself * (sh.y + sl.y) + bv.y);
        *(float2*)(out + (size_t)node * 256 + ch) = o;
    }
}

// ---------------- launch ----------------

static inline char* align16(char* p) { return (char*)(((size_t)p + 15) & ~(size_t)15); }

extern "C" void kernel_launch(void* const* d_in, const int* in_sizes, int n_in,
                              void* d_out, int out_size, void* d_ws, size_t ws_size,
                              hipStream_t stream) {
    const float* x  = (const float*)d_in[0];
    const int* eidx = (const int*)d_in[1];
    const float* W1 = (const float*)d_in[2];
    const float* b1 = (const float*)d_in[3];
    const float* W2 = (const float*)d_in[4];
    const float* b2 = (const float*)d_in[5];
    const float* W3 = (const float*)d_in[6];
    const float* b3 = (const float*)d_in[7];
    float* out = (float*)d_out;

    const int* src = eidx;
    const int* dst = eidx + N_EDGES;

    char* ws = (char*)d_ws;
    unsigned short* A2 = (unsigned short*)ws;  ws += (size_t)MPAD * KPHYS * 2;   // 102.5 MB
    __half* Chi = (__half*)ws;                 ws += (size_t)MPAD * 512 * 2;      // 51.2 MB
    __half* Clo = (__half*)ws;                 ws += (size_t)MPAD * 512 * 2;      // 51.2 MB
    unsigned short* B2T1 = (unsigned short*)ws; ws += (size_t)512 * KB * 2;
    unsigned short* B2T2 = (unsigned short*)ws; ws += (size_t)512 * KB * 2;
    unsigned short* B2T3 = (unsigned short*)ws; ws += (size_t)256 * KB * 2;
    int* deg = (int*)ws;        ws = align16(ws + (size_t)N_NODES * 4);
    float* dinv = (float*)ws;   ws = align16(ws + (size_t)N_NODES * 4);
    int* offsets = (int*)ws;    ws = align16(ws + (size_t)(N_NODES + 1) * 4);
    int* cursor = (int*)ws;     ws = align16(ws + (size_t)N_NODES * 4);
    int2* csr_sw = (int2*)ws;   ws = align16(ws + (size_t)N_EDGES * 8);
    int* local_scan = (int*)ws; ws = align16(ws + (size_t)N_NODES * 4);
    int* partials = (int*)ws;   ws = align16(ws + (size_t)SCANB * 4);

    // ---- CSR build ----
    zero_int_kernel<<<(N_NODES + 255) / 256, 256, 0, stream>>>(deg, N_NODES);
    count_deg_kernel<<<(N_EDGES + 255) / 256, 256, 0, stream>>>(dst, deg);
    dinv_kernel<<<(N_NODES + 255) / 256, 256, 0, stream>>>(deg, dinv);
    scan1_kernel<<<SCANB, 256, 0, stream>>>(deg, local_scan, partials);
    scan2_kernel<<<1, 256, 0, stream>>>(partials);
    scan3_kernel<<<SCANB, 256, 0, stream>>>(deg, local_scan, partials, offsets, cursor);
    fill_csr_kernel<<<(N_EDGES + 255) / 256, 256, 0, stream>>>(src, dst, cursor, csr_sw, dinv);

    // ---- weight + input splits ----
    wsplit_kernel<<<(512 * 512 + 255) / 256, 256, 0, stream>>>(W1, B2T1, 512);
    wsplit_kernel<<<(512 * 512 + 255) / 256, 256, 0, stream>>>(W2, B2T2, 512);
    wsplit_kernel<<<(512 * 256 + 255) / 256, 256, 0, stream>>>(W3, B2T3, 256);
    split_x_kernel<<<MPAD, 256, 0, stream>>>(x, A2);

    // XCD-affine GEMM grids: blocks = 8 * ceil(NBANDS/8) * ncolb
    const int gemm_grid_512 = 8 * ((NBANDS + 7) / 8) * 4;  // 1568
    const int gemm_grid_256 = 8 * ((NBANDS + 7) / 8) * 2;  // 784

    // sliced aggregate grids: 8 slices x (nodes/4) groups, 4 nodes per block
    const int agg_grid = 8 * (MPAD / 4);                  // 100096
    const int aggf_grid = 8 * ((N_NODES + 3) / 4);        // 100000

    // ---- layer 1 ----
    {
        gemm_split_bt<<<gemm_grid_512, 256, 0, stream>>>(A2, B2T1, Chi, Clo, 512, 2);
        aggregate_split_kernel<<<agg_grid, 256, 0, stream>>>(Chi, Clo, offsets, csr_sw, dinv, b1, A2);
    }
    // ---- layer 2 ----
    {
        gemm_split_bt<<<gemm_grid_512, 256, 0, stream>>>(A2, B2T2, Chi, Clo, 512, 2);
        aggregate_split_kernel<<<agg_grid, 256, 0, stream>>>(Chi, Clo, offsets, csr_sw, dinv, b2, A2);
    }
    // ---- layer 3 ----
    {
        gemm_split_bt<<<gemm_grid_256, 256, 0, stream>>>(A2, B2T3, Chi, Clo, 256, 1);
        aggregate_final_kernel<<<aggf_grid, 256, 0, stream>>>(Chi, Clo, offsets, csr_sw, dinv, b3, out);
    }
}

// Round 7
// 1033.688 us; speedup vs baseline: 1.2913x; 1.2913x over previous
//
#include <hip/hip_runtime.h>
#include <hip/hip_fp16.h>
#include <math.h>

#define N_NODES 50000
#define N_EDGES 800000
#define MPAD 50048            // 391 * 128, so GEMM needs no M bounds checks
#define NBANDS (MPAD / 128)   // 391 row bands
#define KPHYS 1024            // A2 physical row width: [hi(512) | lo(512)]
#define KB 1024               // B2T physical row width: [hi(512) | lo(512)]
#define NOUTER 16             // 16 outer iters x 32 cols = 512 K
#define SCANB ((N_NODES + 255) / 256)  // 196 scan blocks

// ---------------- bf16 helpers ----------------

__device__ __forceinline__ unsigned short bf16_rn(float f) {
    unsigned u = __float_as_uint(f);
    u += 0x7FFFu + ((u >> 16) & 1u);  // round-to-nearest-even
    return (unsigned short)(u >> 16);
}
__device__ __forceinline__ float bf16_f32(unsigned short h) {
    return __uint_as_float(((unsigned)h) << 16);
}

typedef __attribute__((ext_vector_type(2))) float f2v;

__device__ __forceinline__ float2 ntload2(const float* p) {
    f2v v = __builtin_nontemporal_load((const f2v*)p);
    return make_float2(v[0], v[1]);
}

// ---------------- degree / CSR build ----------------

__global__ void zero_int_kernel(int* __restrict__ p, int n) {
    int i = blockIdx.x * blockDim.x + threadIdx.x;
    if (i < n) p[i] = 0;
}

__global__ void count_deg_kernel(const int* __restrict__ dst, int* __restrict__ deg) {
    int e = blockIdx.x * blockDim.x + threadIdx.x;
    if (e < N_EDGES) atomicAdd(&deg[dst[e]], 1);
}

__global__ void dinv_kernel(const int* __restrict__ deg, float* __restrict__ dinv) {
    int i = blockIdx.x * blockDim.x + threadIdx.x;
    if (i < N_NODES) dinv[i] = rsqrtf((float)deg[i] + 1.0f);  // +1 self-loop
}

// 3-kernel scan (multi-block)
__global__ __launch_bounds__(256) void scan1_kernel(const int* __restrict__ deg,
                                                    int* __restrict__ local_scan,
                                                    int* __restrict__ partials) {
    __shared__ int sm[256];
    int b = blockIdx.x, t = threadIdx.x;
    int i = b * 256 + t;
    int v = (i < N_NODES) ? deg[i] : 0;
    sm[t] = v;
    __syncthreads();
    for (int off = 1; off < 256; off <<= 1) {
        int x = (t >= off) ? sm[t - off] : 0;
        __syncthreads();
        sm[t] += x;
        __syncthreads();
    }
    if (i < N_NODES) local_scan[i] = sm[t];
    if (t == 255) partials[b] = sm[255];
}

__global__ __launch_bounds__(256) void scan2_kernel(int* __restrict__ partials) {
    __shared__ int sm[256];
    int t = threadIdx.x;
    sm[t] = (t < SCANB) ? partials[t] : 0;
    __syncthreads();
    for (int off = 1; off < 256; off <<= 1) {
        int x = (t >= off) ? sm[t - off] : 0;
        __syncthreads();
        sm[t] += x;
        __syncthreads();
    }
    if (t < SCANB) partials[t] = (t == 0) ? 0 : sm[t - 1];  // exclusive
}

__global__ __launch_bounds__(256) void scan3_kernel(const int* __restrict__ deg,
                                                    const int* __restrict__ local_scan,
                                                    const int* __restrict__ partials,
                                                    int* __restrict__ offsets,
                                                    int* __restrict__ cursor) {
    int i = blockIdx.x * 256 + threadIdx.x;
    if (i == 0) offsets[0] = 0;
    if (i < N_NODES) {
        int incl = local_scan[i] + partials[blockIdx.x];
        offsets[i + 1] = incl;
        cursor[i] = incl - deg[i];
    }
}

// packed CSR entry: {src, weight-as-bits} -> one 8B load per edge
__global__ void fill_csr_kernel(const int* __restrict__ src, const int* __restrict__ dst,
                                int* __restrict__ cursor, int2* __restrict__ csr_sw,
                                const float* __restrict__ dinv) {
    int e = blockIdx.x * blockDim.x + threadIdx.x;
    if (e < N_EDGES) {
        int s = src[e], d = dst[e];
        int p = atomicAdd(&cursor[d], 1);
        csr_sw[p] = make_int2(s, __float_as_int(dinv[s] * dinv[d]));
    }
}

// ---------------- split-bf16 MFMA GEMM (fp16 hi/lo output) ----------------
// R6: 3-buffer LDS rotation, prefetch distance 2, counted vmcnt + raw barrier
// (T3/T4). The old __syncthreads compiled to s_waitcnt vmcnt(0) -> every iter
// drained the stage issued only ~1 body earlier vs ~900cy HBM latency (MfmaUtil
// 21%). Now: stage for it+2 issues at iter top; vmcnt(8) keeps the newest 8
// loads flying and waits only the 2-bodies-old stage of cur. Safety: stage at
// iter i writes buf (i+2)%3 == (i-1)%3, whose ds_reads were MFMA-consumed
// before barrier(i); per-wave vmcnt before barrier => cur fully landed
// block-wide after barrier. LDS 96KiB -> 1 block/CU.

typedef __attribute__((ext_vector_type(8))) short bf16x8;
typedef __attribute__((ext_vector_type(4))) float floatx4;

#define GLL16(g, l)                                                                   \
    __builtin_amdgcn_global_load_lds((__attribute__((address_space(1))) const void*)(g), \
                                     (__attribute__((address_space(3))) void*)(l), 16, 0, 0)

__global__ __launch_bounds__(256) void gemm_split_bt(const unsigned short* __restrict__ A2,
                                                     const unsigned short* __restrict__ B2T,
                                                     __half* __restrict__ Chi,
                                                     __half* __restrict__ Clo, int N,
                                                     int cshift) {
    // XCD-affine decode (cshift = log2(ncol_blocks): 2 for N=512, 1 for N=256)
    const int b = blockIdx.x;
    const int xcd = b & 7;
    const int q = b >> 3;
    const int cb = q & ((1 << cshift) - 1);
    const int bh = q >> cshift;
    const int r = bh * 8 + xcd;
    if (r >= NBANDS) return;
    const int row0 = r * 128;
    const int col0 = cb * 128;

    // [buf][hi/lo] 128x32 chunks, triple-buffered: 96 KiB total
    __shared__ unsigned short As[3][2][128 * 32];
    __shared__ unsigned short Bs[3][2][128 * 32];

    const int t = threadIdx.x;
    const int lane = t & 63;
    const int quad = lane >> 4;
    const int l15 = lane & 15;
    const int w = t >> 6;
    const int wm = w & 1, wn = w >> 1;

    floatx4 acc[4][4];
#pragma unroll
    for (int i = 0; i < 4; i++)
#pragma unroll
        for (int j = 0; j < 4; j++) acc[i][j] = (floatx4){0.f, 0.f, 0.f, 0.f};

    // coalesced staging with XOR-swizzled k-chunk
    const int sr = t >> 2;
    const int sk = ((t & 3) ^ ((t >> 3) & 3)) * 8;
    const unsigned short* Arow0 = A2 + (size_t)(row0 + sr) * KPHYS + sk;
    const unsigned short* Arow1 = Arow0 + (size_t)64 * KPHYS;
    const unsigned short* Brow0 = B2T + (size_t)(col0 + sr) * KB + sk;
    const unsigned short* Brow1 = Brow0 + (size_t)64 * KB;

    // fragment-read swizzle: chunk column = quad ^ ((l15>>1)&3)
    const int fcol = (quad ^ ((l15 >> 1) & 3)) * 8;

#define STAGE(buf, k32)                                            \
    do {                                                           \
        GLL16(Arow0 + (k32), As[buf][0] + t * 8);                  \
        GLL16(Arow1 + (k32), As[buf][0] + 2048 + t * 8);           \
        GLL16(Arow0 + 512 + (k32), As[buf][1] + t * 8);            \
        GLL16(Arow1 + 512 + (k32), As[buf][1] + 2048 + t * 8);     \
        GLL16(Brow0 + (k32), Bs[buf][0] + t * 8);                  \
        GLL16(Brow1 + (k32), Bs[buf][0] + 2048 + t * 8);           \
        GLL16(Brow0 + 512 + (k32), Bs[buf][1] + t * 8);            \
        GLL16(Brow1 + 512 + (k32), Bs[buf][1] + 2048 + t * 8);     \
    } while (0)

    // prologue: stage chunks 0 and 1 (prefetch depth 2)
    STAGE(0, 0);
    STAGE(1, 32);

    for (int it = 0; it < NOUTER; it++) {
        const int cur = it % 3;
        // wait only the 2-iter-old stage of cur; keep the newest 8 loads flying
        if (it < NOUTER - 1)
            asm volatile("s_waitcnt vmcnt(8)" ::: "memory");
        else
            asm volatile("s_waitcnt vmcnt(0)" ::: "memory");
        __builtin_amdgcn_s_barrier();       // cur fully populated block-wide
        __builtin_amdgcn_sched_barrier(0);  // pin ds_reads below the barrier
        if (it + 2 < NOUTER) STAGE((it + 2) % 3, (it + 2) * 32);

        bf16x8 afh[4], afl[4], bfh[4], bfl[4];
#pragma unroll
        for (int mt = 0; mt < 4; mt++) {
            const int ro = (wm * 64 + mt * 16 + l15) * 32 + fcol;
            afh[mt] = *(const bf16x8*)(As[cur][0] + ro);
            afl[mt] = *(const bf16x8*)(As[cur][1] + ro);
        }
#pragma unroll
        for (int nt = 0; nt < 4; nt++) {
            const int ro = (wn * 64 + nt * 16 + l15) * 32 + fcol;
            bfh[nt] = *(const bf16x8*)(Bs[cur][0] + ro);
            bfl[nt] = *(const bf16x8*)(Bs[cur][1] + ro);
        }
        // pass 1: hi*hi
#pragma unroll
        for (int mt = 0; mt < 4; mt++)
#pragma unroll
            for (int nt = 0; nt < 4; nt++)
                acc[mt][nt] = __builtin_amdgcn_mfma_f32_16x16x32_bf16(afh[mt], bfh[nt], acc[mt][nt], 0, 0, 0);
        // pass 2: lo*hi
#pragma unroll
        for (int mt = 0; mt < 4; mt++)
#pragma unroll
            for (int nt = 0; nt < 4; nt++)
                acc[mt][nt] = __builtin_amdgcn_mfma_f32_16x16x32_bf16(afl[mt], bfh[nt], acc[mt][nt], 0, 0, 0);
        // pass 3: hi*lo
#pragma unroll
        for (int mt = 0; mt < 4; mt++)
#pragma unroll
            for (int nt = 0; nt < 4; nt++)
                acc[mt][nt] = __builtin_amdgcn_mfma_f32_16x16x32_bf16(afh[mt], bfl[nt], acc[mt][nt], 0, 0, 0);
    }
#undef STAGE

#pragma unroll
    for (int mt = 0; mt < 4; mt++) {
#pragma unroll
        for (int rr = 0; rr < 4; rr++) {
            int row = row0 + wm * 64 + mt * 16 + quad * 4 + rr;
            __half* Cph = Chi + (size_t)row * N + col0 + wn * 64 + l15;
            __half* Cpl = Clo + (size_t)row * N + col0 + wn * 64 + l15;
#pragma unroll
            for (int nt = 0; nt < 4; nt++) {
                float a = acc[mt][nt][rr];
                __half hi = __float2half(a);
                __half lo = __float2half(a - __half2float(hi));
                Cph[nt * 16] = hi;
                Cpl[nt * 16] = lo;
            }
        }
    }
}

// ---------------- weight split (W [K x N] fp32 -> B2T [N x KB] bf16) ----------------

__global__ void wsplit_kernel(const float* __restrict__ W, unsigned short* __restrict__ B2T, int N) {
    int idx = blockIdx.x * blockDim.x + threadIdx.x;
    if (idx >= 512 * N) return;
    int k = idx / N, n = idx % N;
    float v = W[(size_t)k * N + n];
    unsigned short hi = bf16_rn(v);
    unsigned short lo = bf16_rn(v - bf16_f32(hi));
    unsigned short* row = B2T + (size_t)n * KB;
    row[k] = hi;
    row[512 + k] = lo;
}

// ---------------- x split (fp32 [N_NODES x 512] -> A2 [MPAD x KPHYS]) ----------------

__global__ __launch_bounds__(256) void split_x_kernel(const float* __restrict__ x,
                                                      unsigned short* __restrict__ A2) {
    int m = blockIdx.x;
    int ch = threadIdx.x * 2;
    unsigned short* arow = A2 + (size_t)m * KPHYS;
    float vx = 0.f, vy = 0.f;
    if (m < N_NODES) {
        float2 v = ntload2(x + (size_t)m * 512 + ch);  // x read exactly once
        vx = v.x;
        vy = v.y;
    }
    unsigned short hx = bf16_rn(vx), hy = bf16_rn(vy);
    arow[ch] = hx;
    arow[ch + 1] = hy;
    arow[512 + ch] = bf16_rn(vx - bf16_f32(hx));
    arow[512 + ch + 1] = bf16_rn(vy - bf16_f32(hy));
}

// ---------------- aggregation (R4-exact: the measured 141us operating point) ----------------

__device__ __forceinline__ float gelu_tanh(float x) {
    float x3 = x * x * x;
    float inner = 0.7978845608028654f * (x + 0.044715f * x3);
    return 0.5f * x * (1.0f + tanhf(inner));
}

// One wave per node: 64 lanes x 8 fp16 ch = 512 ch. 4 nodes per 256-thread block.
// Structural floor: FETCH ~430MB = per-XCD duplication of the random gather;
// R5's channel-slicing cut fetch to 298MB but 8x'd per-edge overhead (305us).
// Full-row 16B/lane gathers win.
__global__ __launch_bounds__(256) void aggregate_split_kernel(
    const __half* __restrict__ Chi, const __half* __restrict__ Clo,
    const int* __restrict__ offsets, const int2* __restrict__ csr_sw,
    const float* __restrict__ dinv,
    const float* __restrict__ bias, unsigned short* __restrict__ A2) {
    int t = threadIdx.x;
    int node = __builtin_amdgcn_readfirstlane(blockIdx.x * 4 + (t >> 6));
    int ch = (t & 63) * 8;
    unsigned short* arow = A2 + (size_t)node * KPHYS;
    if (node >= N_NODES) {  // zero pad rows (16B per store)
        *(uint4*)(arow + ch) = make_uint4(0, 0, 0, 0);
        *(uint4*)(arow + 512 + ch) = make_uint4(0, 0, 0, 0);
        return;
    }
    int p0 = offsets[node], p1 = offsets[node + 1];
    float a[8] = {0.f, 0.f, 0.f, 0.f, 0.f, 0.f, 0.f, 0.f};

    union H8 { float4 f4; __half2 h2[4]; };
    int p = p0;
    int pend8 = p0 + ((p1 - p0) & ~7);
    for (; p < pend8; p += 8) {
        int2 e[8];
#pragma unroll
        for (int j = 0; j < 8; j++) e[j] = csr_sw[p + j];
        H8 v[8];
#pragma unroll
        for (int j = 0; j < 8; j++)
            v[j].f4 = *(const float4*)(Chi + (size_t)e[j].x * 512 + ch);
#pragma unroll
        for (int j = 0; j < 8; j++) {
            float wg = __int_as_float(e[j].y);
#pragma unroll
            for (int q = 0; q < 4; q++) {
                float2 c = __half22float2(v[j].h2[q]);
                a[2 * q] += wg * c.x;
                a[2 * q + 1] += wg * c.y;
            }
        }
    }
    if (p + 4 <= p1) {
        int2 e[4];
#pragma unroll
        for (int j = 0; j < 4; j++) e[j] = csr_sw[p + j];
        H8 v[4];
#pragma unroll
        for (int j = 0; j < 4; j++)
            v[j].f4 = *(const float4*)(Chi + (size_t)e[j].x * 512 + ch);
#pragma unroll
        for (int j = 0; j < 4; j++) {
            float wg = __int_as_float(e[j].y);
#pragma unroll
            for (int q = 0; q < 4; q++) {
                float2 c = __half22float2(v[j].h2[q]);
                a[2 * q] += wg * c.x;
                a[2 * q + 1] += wg * c.y;
            }
        }
        p += 4;
    }
    for (; p < p1; p++) {
        int2 e = csr_sw[p];
        float wg = __int_as_float(e.y);
        H8 v;
        v.f4 = *(const float4*)(Chi + (size_t)e.x * 512 + ch);
#pragma unroll
        for (int q = 0; q < 4; q++) {
            float2 c = __half22float2(v.h2[q]);
            a[2 * q] += wg * c.x;
            a[2 * q + 1] += wg * c.y;
        }
    }

    float di = dinv[node];
    float wself = di * di;
    H8 vh, vl;
    vh.f4 = *(const float4*)(Chi + (size_t)node * 512 + ch);
    vl.f4 = *(const float4*)(Clo + (size_t)node * 512 + ch);
    float4 bv0 = *(const float4*)(bias + ch);
    float4 bv1 = *(const float4*)(bias + ch + 4);
    float s[8], b[8] = {bv0.x, bv0.y, bv0.z, bv0.w, bv1.x, bv1.y, bv1.z, bv1.w};
#pragma unroll
    for (int j = 0; j < 4; j++) {
        float2 ch2 = __half22float2(vh.h2[j]);
        float2 cl2 = __half22float2(vl.h2[j]);
        s[2 * j] = ch2.x + cl2.x;
        s[2 * j + 1] = ch2.y + cl2.y;
    }

    unsigned short hi[8], lo[8];
#pragma unroll
    for (int j = 0; j < 8; j++) {
        float v = gelu_tanh(a[j] + wself * s[j] + b[j]);
        hi[j] = bf16_rn(v);
        lo[j] = bf16_rn(v - bf16_f32(hi[j]));
    }
    *(ushort4*)(arow + ch) = make_ushort4(hi[0], hi[1], hi[2], hi[3]);
    *(ushort4*)(arow + ch + 4) = make_ushort4(hi[4], hi[5], hi[6], hi[7]);
    *(ushort4*)(arow + 512 + ch) = make_ushort4(lo[0], lo[1], lo[2], lo[3]);
    *(ushort4*)(arow + 512 + ch + 4) = make_ushort4(lo[4], lo[5], lo[6], lo[7]);
}

// Final agg: 256 ch, one wave per node (64 lanes x 4 fp16 ch), 4 nodes/block.
__global__ __launch_bounds__(256) void aggregate_final_kernel(
    const __half* __restrict__ Chi, const __half* __restrict__ Clo,
    const int* __restrict__ offsets, const int2* __restrict__ csr_sw,
    const float* __restrict__ dinv,
    const float* __restrict__ bias, float* __restrict__ out) {
    int t = threadIdx.x;
    int node = __builtin_amdgcn_readfirstlane(blockIdx.x * 4 + (t >> 6));
    if (node >= N_NODES) return;
    int ch = (t & 63) * 4;
    int p0 = offsets[node], p1 = offsets[node + 1];
    float ax = 0.f, ay = 0.f, az = 0.f, aw = 0.f;

    union H4 { float2 f2; __half2 h2[2]; };
    int p = p0;
    int pend8 = p0 + ((p1 - p0) & ~7);
    for (; p < pend8; p += 8) {
        int2 e[8];
#pragma unroll
        for (int j = 0; j < 8; j++) e[j] = csr_sw[p + j];
        H4 v[8];
#pragma unroll
        for (int j = 0; j < 8; j++)
            v[j].f2 = *(const float2*)(Chi + (size_t)e[j].x * 256 + ch);
#pragma unroll
        for (int j = 0; j < 8; j++) {
            float wg = __int_as_float(e[j].y);
            float2 c0 = __half22float2(v[j].h2[0]), c1 = __half22float2(v[j].h2[1]);
            ax += wg * c0.x; ay += wg * c0.y; az += wg * c1.x; aw += wg * c1.y;
        }
    }
    for (; p < p1; p++) {
        int2 e = csr_sw[p];
        float wg = __int_as_float(e.y);
        H4 v;
        v.f2 = *(const float2*)(Chi + (size_t)e.x * 256 + ch);
        float2 c0 = __half22float2(v.h2[0]), c1 = __half22float2(v.h2[1]);
        ax += wg * c0.x; ay += wg * c0.y; az += wg * c1.x; aw += wg * c1.y;
    }

    float di = dinv[node];
    float wself = di * di;
    H4 vh, vl;
    vh.f2 = *(const float2*)(Chi + (size_t)node * 256 + ch);
    vl.f2 = *(const float2*)(Clo + (size_t)node * 256 + ch);
    float2 h0 = __half22float2(vh.h2[0]), h1 = __half22float2(vh.h2[1]);
    float2 l0 = __half22float2(vl.h2[0]), l1 = __half22float2(vl.h2[1]);
    float4 bv = *(const float4*)(bias + ch);
    float4 o = make_float4(ax + wself * (h0.x + l0.x) + bv.x,
                           ay + wself * (h0.y + l0.y) + bv.y,
                           az + wself * (h1.x + l1.x) + bv.z,
                           aw + wself * (h1.y + l1.y) + bv.w);
    *(float4*)(out + (size_t)node * 256 + ch) = o;
}

// ---------------- launch ----------------

static inline char* align16(char* p) { return (char*)(((size_t)p + 15) & ~(size_t)15); }

extern "C" void kernel_launch(void* const* d_in, const int* in_sizes, int n_in,
                              void* d_out, int out_size, void* d_ws, size_t ws_size,
                              hipStream_t stream) {
    const float* x  = (const float*)d_in[0];
    const int* eidx = (const int*)d_in[1];
    const float* W1 = (const float*)d_in[2];
    const float* b1 = (const float*)d_in[3];
    const float* W2 = (const float*)d_in[4];
    const float* b2 = (const float*)d_in[5];
    const float* W3 = (const float*)d_in[6];
    const float* b3 = (const float*)d_in[7];
    float* out = (float*)d_out;

    const int* src = eidx;
    const int* dst = eidx + N_EDGES;

    char* ws = (char*)d_ws;
    unsigned short* A2 = (unsigned short*)ws;  ws += (size_t)MPAD * KPHYS * 2;   // 102.5 MB
    __half* Chi = (__half*)ws;                 ws += (size_t)MPAD * 512 * 2;      // 51.2 MB
    __half* Clo = (__half*)ws;                 ws += (size_t)MPAD * 512 * 2;      // 51.2 MB
    unsigned short* B2T1 = (unsigned short*)ws; ws += (size_t)512 * KB * 2;
    unsigned short* B2T2 = (unsigned short*)ws; ws += (size_t)512 * KB * 2;
    unsigned short* B2T3 = (unsigned short*)ws; ws += (size_t)256 * KB * 2;
    int* deg = (int*)ws;        ws = align16(ws + (size_t)N_NODES * 4);
    float* dinv = (float*)ws;   ws = align16(ws + (size_t)N_NODES * 4);
    int* offsets = (int*)ws;    ws = align16(ws + (size_t)(N_NODES + 1) * 4);
    int* cursor = (int*)ws;     ws = align16(ws + (size_t)N_NODES * 4);
    int2* csr_sw = (int2*)ws;   ws = align16(ws + (size_t)N_EDGES * 8);
    int* local_scan = (int*)ws; ws = align16(ws + (size_t)N_NODES * 4);
    int* partials = (int*)ws;   ws = align16(ws + (size_t)SCANB * 4);

    // ---- CSR build ----
    zero_int_kernel<<<(N_NODES + 255) / 256, 256, 0, stream>>>(deg, N_NODES);
    count_deg_kernel<<<(N_EDGES + 255) / 256, 256, 0, stream>>>(dst, deg);
    dinv_kernel<<<(N_NODES + 255) / 256, 256, 0, stream>>>(deg, dinv);
    scan1_kernel<<<SCANB, 256, 0, stream>>>(deg, local_scan, partials);
    scan2_kernel<<<1, 256, 0, stream>>>(partials);
    scan3_kernel<<<SCANB, 256, 0, stream>>>(deg, local_scan, partials, offsets, cursor);
    fill_csr_kernel<<<(N_EDGES + 255) / 256, 256, 0, stream>>>(src, dst, cursor, csr_sw, dinv);

    // ---- weight + input splits ----
    wsplit_kernel<<<(512 * 512 + 255) / 256, 256, 0, stream>>>(W1, B2T1, 512);
    wsplit_kernel<<<(512 * 512 + 255) / 256, 256, 0, stream>>>(W2, B2T2, 512);
    wsplit_kernel<<<(512 * 256 + 255) / 256, 256, 0, stream>>>(W3, B2T3, 256);
    split_x_kernel<<<MPAD, 256, 0, stream>>>(x, A2);

    // XCD-affine GEMM grids: blocks = 8 * ceil(NBANDS/8) * ncolb
    const int gemm_grid_512 = 8 * ((NBANDS + 7) / 8) * 4;  // 1568
    const int gemm_grid_256 = 8 * ((NBANDS + 7) / 8) * 2;  // 784

    // ---- layer 1 ----
    {
        gemm_split_bt<<<gemm_grid_512, 256, 0, stream>>>(A2, B2T1, Chi, Clo, 512, 2);
        aggregate_split_kernel<<<MPAD / 4, 256, 0, stream>>>(Chi, Clo, offsets, csr_sw, dinv, b1, A2);
    }
    // ---- layer 2 ----
    {
        gemm_split_bt<<<gemm_grid_512, 256, 0, stream>>>(A2, B2T2, Chi, Clo, 512, 2);
        aggregate_split_kernel<<<MPAD / 4, 256, 0, stream>>>(Chi, Clo, offsets, csr_sw, dinv, b2, A2);
    }
    // ---- layer 3 ----
    {
        gemm_split_bt<<<gemm_grid_256, 256, 0, stream>>>(A2, B2T3, Chi, Clo, 256, 1);
        aggregate_final_kernel<<<MPAD / 4, 256, 0, stream>>>(Chi, Clo, offsets, csr_sw, dinv, b3, out);
    }
}

// Round 8
// 863.020 us; speedup vs baseline: 1.5467x; 1.1978x over previous
//
#include <hip/hip_runtime.h>
#include <hip/hip_fp16.h>
#include <math.h>

#define N_NODES 50000
#define N_EDGES 800000
#define MPAD 50176            // 196 * 256: GEMM 256-row tiles, no M bounds checks
#define MT256 (MPAD / 256)    // 196 row tiles
#define KPHYS 1024            // A2 physical row width: [hi(512) | lo(512)]
#define KB 1024               // B2T physical row width: [hi(512) | lo(512)]
#define NOUTER 16             // 16 outer iters x 32 cols = 512 K
#define SCANB ((N_NODES + 255) / 256)  // 196 scan blocks

// ---------------- bf16 helpers ----------------

__device__ __forceinline__ unsigned short bf16_rn(float f) {
    unsigned u = __float_as_uint(f);
    u += 0x7FFFu + ((u >> 16) & 1u);  // round-to-nearest-even
    return (unsigned short)(u >> 16);
}
__device__ __forceinline__ float bf16_f32(unsigned short h) {
    return __uint_as_float(((unsigned)h) << 16);
}

typedef __attribute__((ext_vector_type(2))) float f2v;

__device__ __forceinline__ float2 ntload2(const float* p) {
    f2v v = __builtin_nontemporal_load((const f2v*)p);
    return make_float2(v[0], v[1]);
}

// ---------------- degree / CSR build ----------------

__global__ void zero_int_kernel(int* __restrict__ p, int n) {
    int i = blockIdx.x * blockDim.x + threadIdx.x;
    if (i < n) p[i] = 0;
}

__global__ void count_deg_kernel(const int* __restrict__ dst, int* __restrict__ deg) {
    int e = blockIdx.x * blockDim.x + threadIdx.x;
    if (e < N_EDGES) atomicAdd(&deg[dst[e]], 1);
}

__global__ void dinv_kernel(const int* __restrict__ deg, float* __restrict__ dinv) {
    int i = blockIdx.x * blockDim.x + threadIdx.x;
    if (i < N_NODES) dinv[i] = rsqrtf((float)deg[i] + 1.0f);  // +1 self-loop
}

// 3-kernel scan (multi-block)
__global__ __launch_bounds__(256) void scan1_kernel(const int* __restrict__ deg,
                                                    int* __restrict__ local_scan,
                                                    int* __restrict__ partials) {
    __shared__ int sm[256];
    int b = blockIdx.x, t = threadIdx.x;
    int i = b * 256 + t;
    int v = (i < N_NODES) ? deg[i] : 0;
    sm[t] = v;
    __syncthreads();
    for (int off = 1; off < 256; off <<= 1) {
        int x = (t >= off) ? sm[t - off] : 0;
        __syncthreads();
        sm[t] += x;
        __syncthreads();
    }
    if (i < N_NODES) local_scan[i] = sm[t];
    if (t == 255) partials[b] = sm[255];
}

__global__ __launch_bounds__(256) void scan2_kernel(int* __restrict__ partials) {
    __shared__ int sm[256];
    int t = threadIdx.x;
    sm[t] = (t < SCANB) ? partials[t] : 0;
    __syncthreads();
    for (int off = 1; off < 256; off <<= 1) {
        int x = (t >= off) ? sm[t - off] : 0;
        __syncthreads();
        sm[t] += x;
        __syncthreads();
    }
    if (t < SCANB) partials[t] = (t == 0) ? 0 : sm[t - 1];  // exclusive
}

__global__ __launch_bounds__(256) void scan3_kernel(const int* __restrict__ deg,
                                                    const int* __restrict__ local_scan,
                                                    const int* __restrict__ partials,
                                                    int* __restrict__ offsets,
                                                    int* __restrict__ cursor) {
    int i = blockIdx.x * 256 + threadIdx.x;
    if (i == 0) offsets[0] = 0;
    if (i < N_NODES) {
        int incl = local_scan[i] + partials[blockIdx.x];
        offsets[i + 1] = incl;
        cursor[i] = incl - deg[i];
    }
}

// packed CSR entry: {src, weight-as-bits} -> one 8B load per edge
__global__ void fill_csr_kernel(const int* __restrict__ src, const int* __restrict__ dst,
                                int* __restrict__ cursor, int2* __restrict__ csr_sw,
                                const float* __restrict__ dinv) {
    int e = blockIdx.x * blockDim.x + threadIdx.x;
    if (e < N_EDGES) {
        int s = src[e], d = dst[e];
        int p = atomicAdd(&cursor[d], 1);
        csr_sw[p] = make_int2(s, __float_as_int(dinv[s] * dinv[d]));
    }
}

// ---------------- split-bf16 MFMA GEMM (fp16 hi/lo output) ----------------
// R7: 256x256 tile, 8 waves (512 thr), wave tile 128x64, BK=32 double-buffer.
// Same staging/swizzle/fragment algebra as the proven 128^2 kernel (the XOR
// key (row>>1)&3 is invariant under +128-row offsets), but fragment ratio
// rises 3 -> 4 MFMA per ds_read and FLOP-per-barrier rises 4x. LDS 128 KiB ->
// 1 block/CU x 8 waves (2/SIMD, same waves/CU as R4's 2 x 4-wave blocks).
// R6's triple-buffer (4 waves/CU) regressed; FETCH=71MB showed loads L2-hit,
// so work-per-barrier, not load latency, is the lever.

typedef __attribute__((ext_vector_type(8))) short bf16x8;
typedef __attribute__((ext_vector_type(4))) float floatx4;

#define GLL16(g, l)                                                                   \
    __builtin_amdgcn_global_load_lds((__attribute__((address_space(1))) const void*)(g), \
                                     (__attribute__((address_space(3))) void*)(l), 16, 0, 0)

__global__ __launch_bounds__(512, 2) void gemm_split_bt(const unsigned short* __restrict__ A2,
                                                        const unsigned short* __restrict__ B2T,
                                                        __half* __restrict__ Chi,
                                                        __half* __restrict__ Clo, int N,
                                                        int cshift) {
    // XCD-affine decode (cshift = log2(ncol_tiles): 1 for N=512, 0 for N=256)
    const int b = blockIdx.x;
    const int xcd = b & 7;
    const int q = b >> 3;
    const int cb = q & ((1 << cshift) - 1);
    const int bh = q >> cshift;
    const int r = bh * 8 + xcd;
    if (r >= MT256) return;
    const int row0 = r * 256;
    const int col0 = cb * 256;

    // [buf][hi/lo] 256x32 chunks, double-buffered: 128 KiB total
    __shared__ unsigned short As[2][2][256 * 32];
    __shared__ unsigned short Bs[2][2][256 * 32];

    const int t = threadIdx.x;
    const int lane = t & 63;
    const int quad = lane >> 4;
    const int l15 = lane & 15;
    const int w = t >> 6;
    const int wm = w >> 2, wn = w & 3;  // 2 x 4 wave grid, wave tile 128x64

    floatx4 acc[8][4];
#pragma unroll
    for (int i = 0; i < 8; i++)
#pragma unroll
        for (int j = 0; j < 4; j++) acc[i][j] = (floatx4){0.f, 0.f, 0.f, 0.f};

    // coalesced staging with XOR-swizzled k-chunk (512 thr -> rows 0..127 per GLL16)
    const int sr = t >> 2;
    const int sk = ((t & 3) ^ ((t >> 3) & 3)) * 8;
    const unsigned short* Arow0 = A2 + (size_t)(row0 + sr) * KPHYS + sk;
    const unsigned short* Arow1 = Arow0 + (size_t)128 * KPHYS;
    const unsigned short* Brow0 = B2T + (size_t)(col0 + sr) * KB + sk;
    const unsigned short* Brow1 = Brow0 + (size_t)128 * KB;

    // fragment-read swizzle: chunk column = quad ^ ((l15>>1)&3)
    const int fcol = (quad ^ ((l15 >> 1) & 3)) * 8;

#define STAGE(buf, k32)                                            \
    do {                                                           \
        GLL16(Arow0 + (k32), As[buf][0] + t * 8);                  \
        GLL16(Arow1 + (k32), As[buf][0] + 4096 + t * 8);           \
        GLL16(Arow0 + 512 + (k32), As[buf][1] + t * 8);            \
        GLL16(Arow1 + 512 + (k32), As[buf][1] + 4096 + t * 8);     \
        GLL16(Brow0 + (k32), Bs[buf][0] + t * 8);                  \
        GLL16(Brow1 + (k32), Bs[buf][0] + 4096 + t * 8);           \
        GLL16(Brow0 + 512 + (k32), Bs[buf][1] + t * 8);            \
        GLL16(Brow1 + 512 + (k32), Bs[buf][1] + 4096 + t * 8);     \
    } while (0)

    // prologue: stage chunk 0 into buffer 0
    STAGE(0, 0);

    for (int it = 0; it < NOUTER; it++) {
        const int cur = it & 1;
        __syncthreads();  // drains prefetch into cur; all reads of cur^1 done
        if (it + 1 < NOUTER) STAGE(cur ^ 1, (it + 1) * 32);

        bf16x8 bfh[4], bfl[4];
#pragma unroll
        for (int nt = 0; nt < 4; nt++) {
            const int ro = (wn * 64 + nt * 16 + l15) * 32 + fcol;
            bfh[nt] = *(const bf16x8*)(Bs[cur][0] + ro);
            bfl[nt] = *(const bf16x8*)(Bs[cur][1] + ro);
        }
#pragma unroll
        for (int mt = 0; mt < 8; mt++) {
            const int ro = (wm * 128 + mt * 16 + l15) * 32 + fcol;
            bf16x8 ah = *(const bf16x8*)(As[cur][0] + ro);
            bf16x8 al = *(const bf16x8*)(As[cur][1] + ro);
#pragma unroll
            for (int nt = 0; nt < 4; nt++)
                acc[mt][nt] = __builtin_amdgcn_mfma_f32_16x16x32_bf16(ah, bfh[nt], acc[mt][nt], 0, 0, 0);
#pragma unroll
            for (int nt = 0; nt < 4; nt++)
                acc[mt][nt] = __builtin_amdgcn_mfma_f32_16x16x32_bf16(al, bfh[nt], acc[mt][nt], 0, 0, 0);
#pragma unroll
            for (int nt = 0; nt < 4; nt++)
                acc[mt][nt] = __builtin_amdgcn_mfma_f32_16x16x32_bf16(ah, bfl[nt], acc[mt][nt], 0, 0, 0);
        }
    }
#undef STAGE

#pragma unroll
    for (int mt = 0; mt < 8; mt++) {
#pragma unroll
        for (int rr = 0; rr < 4; rr++) {
            int row = row0 + wm * 128 + mt * 16 + quad * 4 + rr;
            __half* Cph = Chi + (size_t)row * N + col0 + wn * 64 + l15;
            __half* Cpl = Clo + (size_t)row * N + col0 + wn * 64 + l15;
#pragma unroll
            for (int nt = 0; nt < 4; nt++) {
                float a = acc[mt][nt][rr];
                __half hi = __float2half(a);
                __half lo = __float2half(a - __half2float(hi));
                Cph[nt * 16] = hi;
                Cpl[nt * 16] = lo;
            }
        }
    }
}

// ---------------- weight split (W [K x N] fp32 -> B2T [N x KB] bf16) ----------------

__global__ void wsplit_kernel(const float* __restrict__ W, unsigned short* __restrict__ B2T, int N) {
    int idx = blockIdx.x * blockDim.x + threadIdx.x;
    if (idx >= 512 * N) return;
    int k = idx / N, n = idx % N;
    float v = W[(size_t)k * N + n];
    unsigned short hi = bf16_rn(v);
    unsigned short lo = bf16_rn(v - bf16_f32(hi));
    unsigned short* row = B2T + (size_t)n * KB;
    row[k] = hi;
    row[512 + k] = lo;
}

// ---------------- x split (fp32 [N_NODES x 512] -> A2 [MPAD x KPHYS]) ----------------

__global__ __launch_bounds__(256) void split_x_kernel(const float* __restrict__ x,
                                                      unsigned short* __restrict__ A2) {
    int m = blockIdx.x;
    int ch = threadIdx.x * 2;
    unsigned short* arow = A2 + (size_t)m * KPHYS;
    float vx = 0.f, vy = 0.f;
    if (m < N_NODES) {
        float2 v = ntload2(x + (size_t)m * 512 + ch);  // x read exactly once
        vx = v.x;
        vy = v.y;
    }
    unsigned short hx = bf16_rn(vx), hy = bf16_rn(vy);
    arow[ch] = hx;
    arow[ch + 1] = hy;
    arow[512 + ch] = bf16_rn(vx - bf16_f32(hx));
    arow[512 + ch + 1] = bf16_rn(vy - bf16_f32(hy));
}

// ---------------- aggregation (R4-exact: the measured 141us operating point) ----------------

__device__ __forceinline__ float gelu_tanh(float x) {
    float x3 = x * x * x;
    float inner = 0.7978845608028654f * (x + 0.044715f * x3);
    return 0.5f * x * (1.0f + tanhf(inner));
}

// One wave per node: 64 lanes x 8 fp16 ch = 512 ch. 4 nodes per 256-thread block.
// Structural floor: FETCH ~430MB = per-XCD duplication of the random gather;
// R5's channel-slicing cut fetch to 298MB but 8x'd per-edge overhead (305us).
// Full-row 16B/lane gathers win.
__global__ __launch_bounds__(256) void aggregate_split_kernel(
    const __half* __restrict__ Chi, const __half* __restrict__ Clo,
    const int* __restrict__ offsets, const int2* __restrict__ csr_sw,
    const float* __restrict__ dinv,
    const float* __restrict__ bias, unsigned short* __restrict__ A2) {
    int t = threadIdx.x;
    int node = __builtin_amdgcn_readfirstlane(blockIdx.x * 4 + (t >> 6));
    int ch = (t & 63) * 8;
    unsigned short* arow = A2 + (size_t)node * KPHYS;
    if (node >= N_NODES) {  // zero pad rows (16B per store)
        *(uint4*)(arow + ch) = make_uint4(0, 0, 0, 0);
        *(uint4*)(arow + 512 + ch) = make_uint4(0, 0, 0, 0);
        return;
    }
    int p0 = offsets[node], p1 = offsets[node + 1];
    float a[8] = {0.f, 0.f, 0.f, 0.f, 0.f, 0.f, 0.f, 0.f};

    union H8 { float4 f4; __half2 h2[4]; };
    int p = p0;
    int pend8 = p0 + ((p1 - p0) & ~7);
    for (; p < pend8; p += 8) {
        int2 e[8];
#pragma unroll
        for (int j = 0; j < 8; j++) e[j] = csr_sw[p + j];
        H8 v[8];
#pragma unroll
        for (int j = 0; j < 8; j++)
            v[j].f4 = *(const float4*)(Chi + (size_t)e[j].x * 512 + ch);
#pragma unroll
        for (int j = 0; j < 8; j++) {
            float wg = __int_as_float(e[j].y);
#pragma unroll
            for (int q = 0; q < 4; q++) {
                float2 c = __half22float2(v[j].h2[q]);
                a[2 * q] += wg * c.x;
                a[2 * q + 1] += wg * c.y;
            }
        }
    }
    if (p + 4 <= p1) {
        int2 e[4];
#pragma unroll
        for (int j = 0; j < 4; j++) e[j] = csr_sw[p + j];
        H8 v[4];
#pragma unroll
        for (int j = 0; j < 4; j++)
            v[j].f4 = *(const float4*)(Chi + (size_t)e[j].x * 512 + ch);
#pragma unroll
        for (int j = 0; j < 4; j++) {
            float wg = __int_as_float(e[j].y);
#pragma unroll
            for (int q = 0; q < 4; q++) {
                float2 c = __half22float2(v[j].h2[q]);
                a[2 * q] += wg * c.x;
                a[2 * q + 1] += wg * c.y;
            }
        }
        p += 4;
    }
    for (; p < p1; p++) {
        int2 e = csr_sw[p];
        float wg = __int_as_float(e.y);
        H8 v;
        v.f4 = *(const float4*)(Chi + (size_t)e.x * 512 + ch);
#pragma unroll
        for (int q = 0; q < 4; q++) {
            float2 c = __half22float2(v.h2[q]);
            a[2 * q] += wg * c.x;
            a[2 * q + 1] += wg * c.y;
        }
    }

    float di = dinv[node];
    float wself = di * di;
    H8 vh, vl;
    vh.f4 = *(const float4*)(Chi + (size_t)node * 512 + ch);
    vl.f4 = *(const float4*)(Clo + (size_t)node * 512 + ch);
    float4 bv0 = *(const float4*)(bias + ch);
    float4 bv1 = *(const float4*)(bias + ch + 4);
    float s[8], b[8] = {bv0.x, bv0.y, bv0.z, bv0.w, bv1.x, bv1.y, bv1.z, bv1.w};
#pragma unroll
    for (int j = 0; j < 4; j++) {
        float2 ch2 = __half22float2(vh.h2[j]);
        float2 cl2 = __half22float2(vl.h2[j]);
        s[2 * j] = ch2.x + cl2.x;
        s[2 * j + 1] = ch2.y + cl2.y;
    }

    unsigned short hi[8], lo[8];
#pragma unroll
    for (int j = 0; j < 8; j++) {
        float v = gelu_tanh(a[j] + wself * s[j] + b[j]);
        hi[j] = bf16_rn(v);
        lo[j] = bf16_rn(v - bf16_f32(hi[j]));
    }
    *(ushort4*)(arow + ch) = make_ushort4(hi[0], hi[1], hi[2], hi[3]);
    *(ushort4*)(arow + ch + 4) = make_ushort4(hi[4], hi[5], hi[6], hi[7]);
    *(ushort4*)(arow + 512 + ch) = make_ushort4(lo[0], lo[1], lo[2], lo[3]);
    *(ushort4*)(arow + 512 + ch + 4) = make_ushort4(lo[4], lo[5], lo[6], lo[7]);
}

// Final agg: 256 ch, one wave per node (64 lanes x 4 fp16 ch), 4 nodes/block.
__global__ __launch_bounds__(256) void aggregate_final_kernel(
    const __half* __restrict__ Chi, const __half* __restrict__ Clo,
    const int* __restrict__ offsets, const int2* __restrict__ csr_sw,
    const float* __restrict__ dinv,
    const float* __restrict__ bias, float* __restrict__ out) {
    int t = threadIdx.x;
    int node = __builtin_amdgcn_readfirstlane(blockIdx.x * 4 + (t >> 6));
    if (node >= N_NODES) return;
    int ch = (t & 63) * 4;
    int p0 = offsets[node], p1 = offsets[node + 1];
    float ax = 0.f, ay = 0.f, az = 0.f, aw = 0.f;

    union H4 { float2 f2; __half2 h2[2]; };
    int p = p0;
    int pend8 = p0 + ((p1 - p0) & ~7);
    for (; p < pend8; p += 8) {
        int2 e[8];
#pragma unroll
        for (int j = 0; j < 8; j++) e[j] = csr_sw[p + j];
        H4 v[8];
#pragma unroll
        for (int j = 0; j < 8; j++)
            v[j].f2 = *(const float2*)(Chi + (size_t)e[j].x * 256 + ch);
#pragma unroll
        for (int j = 0; j < 8; j++) {
            float wg = __int_as_float(e[j].y);
            float2 c0 = __half22float2(v[j].h2[0]), c1 = __half22float2(v[j].h2[1]);
            ax += wg * c0.x; ay += wg * c0.y; az += wg * c1.x; aw += wg * c1.y;
        }
    }
    for (; p < p1; p++) {
        int2 e = csr_sw[p];
        float wg = __int_as_float(e.y);
        H4 v;
        v.f2 = *(const float2*)(Chi + (size_t)e.x * 256 + ch);
        float2 c0 = __half22float2(v.h2[0]), c1 = __half22float2(v.h2[1]);
        ax += wg * c0.x; ay += wg * c0.y; az += wg * c1.x; aw += wg * c1.y;
    }

    float di = dinv[node];
    float wself = di * di;
    H4 vh, vl;
    vh.f2 = *(const float2*)(Chi + (size_t)node * 256 + ch);
    vl.f2 = *(const float2*)(Clo + (size_t)node * 256 + ch);
    float2 h0 = __half22float2(vh.h2[0]), h1 = __half22float2(vh.h2[1]);
    float2 l0 = __half22float2(vl.h2[0]), l1 = __half22float2(vl.h2[1]);
    float4 bv = *(const float4*)(bias + ch);
    float4 o = make_float4(ax + wself * (h0.x + l0.x) + bv.x,
                           ay + wself * (h0.y + l0.y) + bv.y,
                           az + wself * (h1.x + l1.x) + bv.z,
                           aw + wself * (h1.y + l1.y) + bv.w);
    *(float4*)(out + (size_t)node * 256 + ch) = o;
}

// ---------------- launch ----------------

static inline char* align16(char* p) { return (char*)(((size_t)p + 15) & ~(size_t)15); }

extern "C" void kernel_launch(void* const* d_in, const int* in_sizes, int n_in,
                              void* d_out, int out_size, void* d_ws, size_t ws_size,
                              hipStream_t stream) {
    const float* x  = (const float*)d_in[0];
    const int* eidx = (const int*)d_in[1];
    const float* W1 = (const float*)d_in[2];
    const float* b1 = (const float*)d_in[3];
    const float* W2 = (const float*)d_in[4];
    const float* b2 = (const float*)d_in[5];
    const float* W3 = (const float*)d_in[6];
    const float* b3 = (const float*)d_in[7];
    float* out = (float*)d_out;

    const int* src = eidx;
    const int* dst = eidx + N_EDGES;

    char* ws = (char*)d_ws;
    unsigned short* A2 = (unsigned short*)ws;  ws += (size_t)MPAD * KPHYS * 2;   // 102.8 MB
    __half* Chi = (__half*)ws;                 ws += (size_t)MPAD * 512 * 2;      // 51.4 MB
    __half* Clo = (__half*)ws;                 ws += (size_t)MPAD * 512 * 2;      // 51.4 MB
    unsigned short* B2T1 = (unsigned short*)ws; ws += (size_t)512 * KB * 2;
    unsigned short* B2T2 = (unsigned short*)ws; ws += (size_t)512 * KB * 2;
    unsigned short* B2T3 = (unsigned short*)ws; ws += (size_t)256 * KB * 2;
    int* deg = (int*)ws;        ws = align16(ws + (size_t)N_NODES * 4);
    float* dinv = (float*)ws;   ws = align16(ws + (size_t)N_NODES * 4);
    int* offsets = (int*)ws;    ws = align16(ws + (size_t)(N_NODES + 1) * 4);
    int* cursor = (int*)ws;     ws = align16(ws + (size_t)N_NODES * 4);
    int2* csr_sw = (int2*)ws;   ws = align16(ws + (size_t)N_EDGES * 8);
    int* local_scan = (int*)ws; ws = align16(ws + (size_t)N_NODES * 4);
    int* partials = (int*)ws;   ws = align16(ws + (size_t)SCANB * 4);

    // ---- CSR build ----
    zero_int_kernel<<<(N_NODES + 255) / 256, 256, 0, stream>>>(deg, N_NODES);
    count_deg_kernel<<<(N_EDGES + 255) / 256, 256, 0, stream>>>(dst, deg);
    dinv_kernel<<<(N_NODES + 255) / 256, 256, 0, stream>>>(deg, dinv);
    scan1_kernel<<<SCANB, 256, 0, stream>>>(deg, local_scan, partials);
    scan2_kernel<<<1, 256, 0, stream>>>(partials);
    scan3_kernel<<<SCANB, 256, 0, stream>>>(deg, local_scan, partials, offsets, cursor);
    fill_csr_kernel<<<(N_EDGES + 255) / 256, 256, 0, stream>>>(src, dst, cursor, csr_sw, dinv);

    // ---- weight + input splits ----
    wsplit_kernel<<<(512 * 512 + 255) / 256, 256, 0, stream>>>(W1, B2T1, 512);
    wsplit_kernel<<<(512 * 512 + 255) / 256, 256, 0, stream>>>(W2, B2T2, 512);
    wsplit_kernel<<<(512 * 256 + 255) / 256, 256, 0, stream>>>(W3, B2T3, 256);
    split_x_kernel<<<MPAD, 256, 0, stream>>>(x, A2);

    // XCD-affine GEMM grids: blocks = 8 * ceil(MT256/8) * ncol_tiles
    const int gemm_grid_512 = 8 * ((MT256 + 7) / 8) * 2;  // 400
    const int gemm_grid_256 = 8 * ((MT256 + 7) / 8) * 1;  // 200

    // ---- layer 1 ----
    {
        gemm_split_bt<<<gemm_grid_512, 512, 0, stream>>>(A2, B2T1, Chi, Clo, 512, 1);
        aggregate_split_kernel<<<MPAD / 4, 256, 0, stream>>>(Chi, Clo, offsets, csr_sw, dinv, b1, A2);
    }
    // ---- layer 2 ----
    {
        gemm_split_bt<<<gemm_grid_512, 512, 0, stream>>>(A2, B2T2, Chi, Clo, 512, 1);
        aggregate_split_kernel<<<MPAD / 4, 256, 0, stream>>>(Chi, Clo, offsets, csr_sw, dinv, b2, A2);
    }
    // ---- layer 3 ----
    {
        gemm_split_bt<<<gemm_grid_256, 512, 0, stream>>>(A2, B2T3, Chi, Clo, 256, 0);
        aggregate_final_kernel<<<MPAD / 4, 256, 0, stream>>>(Chi, Clo, offsets, csr_sw, dinv, b3, out);
    }
}

// Round 9
// 861.309 us; speedup vs baseline: 1.5498x; 1.0020x over previous
//
#include <hip/hip_runtime.h>
#include <hip/hip_fp16.h>
#include <math.h>

#define N_NODES 50000
#define N_EDGES 800000
#define MPAD 50176            // 196 * 256: GEMM 256-row tiles, no M bounds checks
#define MT256 (MPAD / 256)    // 196 row tiles
#define KPHYS 1024            // A2 physical row width: [hi(512) | lo(512)]
#define KB 1024               // B2T physical row width: [hi(512) | lo(512)]
#define NOUTER 16             // 16 outer iters x 32 cols = 512 K
#define SCANB ((N_NODES + 255) / 256)  // 196 scan blocks

// ---------------- bf16 helpers ----------------

__device__ __forceinline__ unsigned short bf16_rn(float f) {
    unsigned u = __float_as_uint(f);
    u += 0x7FFFu + ((u >> 16) & 1u);  // round-to-nearest-even
    return (unsigned short)(u >> 16);
}
__device__ __forceinline__ float bf16_f32(unsigned short h) {
    return __uint_as_float(((unsigned)h) << 16);
}

typedef __attribute__((ext_vector_type(2))) float f2v;
typedef __attribute__((ext_vector_type(4))) float f4v;

__device__ __forceinline__ float2 ntload2(const float* p) {
    f2v v = __builtin_nontemporal_load((const f2v*)p);
    return make_float2(v[0], v[1]);
}
// nt 16B load reinterpreted as 4 half2 (for read-once fp16 self rows)
__device__ __forceinline__ f4v ntload4f(const void* p) {
    return __builtin_nontemporal_load((const f4v*)p);
}
__device__ __forceinline__ int2 ntload_edge(const int2* p) {
    long long raw = __builtin_nontemporal_load((const long long*)p);
    return make_int2((int)(raw & 0xffffffffLL), (int)(raw >> 32));
}

// ---------------- degree / CSR build ----------------

__global__ void zero_int_kernel(int* __restrict__ p, int n) {
    int i = blockIdx.x * blockDim.x + threadIdx.x;
    if (i < n) p[i] = 0;
}

__global__ void count_deg_kernel(const int* __restrict__ dst, int* __restrict__ deg) {
    int e = blockIdx.x * blockDim.x + threadIdx.x;
    if (e < N_EDGES) atomicAdd(&deg[dst[e]], 1);
}

// 3-kernel scan (multi-block); dinv computation folded into scan3
__global__ __launch_bounds__(256) void scan1_kernel(const int* __restrict__ deg,
                                                    int* __restrict__ local_scan,
                                                    int* __restrict__ partials) {
    __shared__ int sm[256];
    int b = blockIdx.x, t = threadIdx.x;
    int i = b * 256 + t;
    int v = (i < N_NODES) ? deg[i] : 0;
    sm[t] = v;
    __syncthreads();
    for (int off = 1; off < 256; off <<= 1) {
        int x = (t >= off) ? sm[t - off] : 0;
        __syncthreads();
        sm[t] += x;
        __syncthreads();
    }
    if (i < N_NODES) local_scan[i] = sm[t];
    if (t == 255) partials[b] = sm[255];
}

__global__ __launch_bounds__(256) void scan2_kernel(int* __restrict__ partials) {
    __shared__ int sm[256];
    int t = threadIdx.x;
    sm[t] = (t < SCANB) ? partials[t] : 0;
    __syncthreads();
    for (int off = 1; off < 256; off <<= 1) {
        int x = (t >= off) ? sm[t - off] : 0;
        __syncthreads();
        sm[t] += x;
        __syncthreads();
    }
    if (t < SCANB) partials[t] = (t == 0) ? 0 : sm[t - 1];  // exclusive
}

__global__ __launch_bounds__(256) void scan3_kernel(const int* __restrict__ deg,
                                                    const int* __restrict__ local_scan,
                                                    const int* __restrict__ partials,
                                                    int* __restrict__ offsets,
                                                    int* __restrict__ cursor,
                                                    float* __restrict__ dinv) {
    int i = blockIdx.x * 256 + threadIdx.x;
    if (i == 0) offsets[0] = 0;
    if (i < N_NODES) {
        int d = deg[i];
        int incl = local_scan[i] + partials[blockIdx.x];
        offsets[i + 1] = incl;
        cursor[i] = incl - d;
        dinv[i] = rsqrtf((float)d + 1.0f);  // +1 self-loop
    }
}

// packed CSR entry: {src, weight-as-bits} -> one 8B load per edge
__global__ void fill_csr_kernel(const int* __restrict__ src, const int* __restrict__ dst,
                                int* __restrict__ cursor, int2* __restrict__ csr_sw,
                                const float* __restrict__ dinv) {
    int e = blockIdx.x * blockDim.x + threadIdx.x;
    if (e < N_EDGES) {
        int s = src[e], d = dst[e];
        int p = atomicAdd(&cursor[d], 1);
        csr_sw[p] = make_int2(s, __float_as_int(dinv[s] * dinv[d]));
    }
}

// ---------------- split-bf16 MFMA GEMM (fp16 hi/lo output) ----------------
// R7 (proven): 256x256 tile, 8 waves, wave tile 128x64, BK=32 double-buffer,
// XCD-affine decode. Unchanged this round (control).

typedef __attribute__((ext_vector_type(8))) short bf16x8;
typedef __attribute__((ext_vector_type(4))) float floatx4;

#define GLL16(g, l)                                                                   \
    __builtin_amdgcn_global_load_lds((__attribute__((address_space(1))) const void*)(g), \
                                     (__attribute__((address_space(3))) void*)(l), 16, 0, 0)

__global__ __launch_bounds__(512, 2) void gemm_split_bt(const unsigned short* __restrict__ A2,
                                                        const unsigned short* __restrict__ B2T,
                                                        __half* __restrict__ Chi,
                                                        __half* __restrict__ Clo, int N,
                                                        int cshift) {
    // XCD-affine decode (cshift = log2(ncol_tiles): 1 for N=512, 0 for N=256)
    const int b = blockIdx.x;
    const int xcd = b & 7;
    const int q = b >> 3;
    const int cb = q & ((1 << cshift) - 1);
    const int bh = q >> cshift;
    const int r = bh * 8 + xcd;
    if (r >= MT256) return;
    const int row0 = r * 256;
    const int col0 = cb * 256;

    // [buf][hi/lo] 256x32 chunks, double-buffered: 128 KiB total
    __shared__ unsigned short As[2][2][256 * 32];
    __shared__ unsigned short Bs[2][2][256 * 32];

    const int t = threadIdx.x;
    const int lane = t & 63;
    const int quad = lane >> 4;
    const int l15 = lane & 15;
    const int w = t >> 6;
    const int wm = w >> 2, wn = w & 3;  // 2 x 4 wave grid, wave tile 128x64

    floatx4 acc[8][4];
#pragma unroll
    for (int i = 0; i < 8; i++)
#pragma unroll
        for (int j = 0; j < 4; j++) acc[i][j] = (floatx4){0.f, 0.f, 0.f, 0.f};

    // coalesced staging with XOR-swizzled k-chunk (512 thr -> rows 0..127 per GLL16)
    const int sr = t >> 2;
    const int sk = ((t & 3) ^ ((t >> 3) & 3)) * 8;
    const unsigned short* Arow0 = A2 + (size_t)(row0 + sr) * KPHYS + sk;
    const unsigned short* Arow1 = Arow0 + (size_t)128 * KPHYS;
    const unsigned short* Brow0 = B2T + (size_t)(col0 + sr) * KB + sk;
    const unsigned short* Brow1 = Brow0 + (size_t)128 * KB;

    // fragment-read swizzle: chunk column = quad ^ ((l15>>1)&3)
    const int fcol = (quad ^ ((l15 >> 1) & 3)) * 8;

#define STAGE(buf, k32)                                            \
    do {                                                           \
        GLL16(Arow0 + (k32), As[buf][0] + t * 8);                  \
        GLL16(Arow1 + (k32), As[buf][0] + 4096 + t * 8);           \
        GLL16(Arow0 + 512 + (k32), As[buf][1] + t * 8);            \
        GLL16(Arow1 + 512 + (k32), As[buf][1] + 4096 + t * 8);     \
        GLL16(Brow0 + (k32), Bs[buf][0] + t * 8);                  \
        GLL16(Brow1 + (k32), Bs[buf][0] + 4096 + t * 8);           \
        GLL16(Brow0 + 512 + (k32), Bs[buf][1] + t * 8);            \
        GLL16(Brow1 + 512 + (k32), Bs[buf][1] + 4096 + t * 8);     \
    } while (0)

    // prologue: stage chunk 0 into buffer 0
    STAGE(0, 0);

    for (int it = 0; it < NOUTER; it++) {
        const int cur = it & 1;
        __syncthreads();  // drains prefetch into cur; all reads of cur^1 done
        if (it + 1 < NOUTER) STAGE(cur ^ 1, (it + 1) * 32);

        bf16x8 bfh[4], bfl[4];
#pragma unroll
        for (int nt = 0; nt < 4; nt++) {
            const int ro = (wn * 64 + nt * 16 + l15) * 32 + fcol;
            bfh[nt] = *(const bf16x8*)(Bs[cur][0] + ro);
            bfl[nt] = *(const bf16x8*)(Bs[cur][1] + ro);
        }
#pragma unroll
        for (int mt = 0; mt < 8; mt++) {
            const int ro = (wm * 128 + mt * 16 + l15) * 32 + fcol;
            bf16x8 ah = *(const bf16x8*)(As[cur][0] + ro);
            bf16x8 al = *(const bf16x8*)(As[cur][1] + ro);
#pragma unroll
            for (int nt = 0; nt < 4; nt++)
                acc[mt][nt] = __builtin_amdgcn_mfma_f32_16x16x32_bf16(ah, bfh[nt], acc[mt][nt], 0, 0, 0);
#pragma unroll
            for (int nt = 0; nt < 4; nt++)
                acc[mt][nt] = __builtin_amdgcn_mfma_f32_16x16x32_bf16(al, bfh[nt], acc[mt][nt], 0, 0, 0);
#pragma unroll
            for (int nt = 0; nt < 4; nt++)
                acc[mt][nt] = __builtin_amdgcn_mfma_f32_16x16x32_bf16(ah, bfl[nt], acc[mt][nt], 0, 0, 0);
        }
    }
#undef STAGE

#pragma unroll
    for (int mt = 0; mt < 8; mt++) {
#pragma unroll
        for (int rr = 0; rr < 4; rr++) {
            int row = row0 + wm * 128 + mt * 16 + quad * 4 + rr;
            __half* Cph = Chi + (size_t)row * N + col0 + wn * 64 + l15;
            __half* Cpl = Clo + (size_t)row * N + col0 + wn * 64 + l15;
#pragma unroll
            for (int nt = 0; nt < 4; nt++) {
                float a = acc[mt][nt][rr];
                __half hi = __float2half(a);
                __half lo = __float2half(a - __half2float(hi));
                Cph[nt * 16] = hi;
                Cpl[nt * 16] = lo;
            }
        }
    }
}

// ---------------- weight split, fused (3 weights, grid-stride) ----------------
// W1 [512x512] -> B2T1, W2 [512x512] -> B2T2, W3 [512x256] -> B2T3

__global__ void wsplit_all_kernel(const float* __restrict__ W1, unsigned short* __restrict__ B2T1,
                                  const float* __restrict__ W2, unsigned short* __restrict__ B2T2,
                                  const float* __restrict__ W3, unsigned short* __restrict__ B2T3) {
    const int total = 512 * 512 + 512 * 512 + 512 * 256;
    for (int idx = blockIdx.x * blockDim.x + threadIdx.x; idx < total;
         idx += gridDim.x * blockDim.x) {
        const float* W;
        unsigned short* B2T;
        int li, N;
        if (idx < 512 * 512) { W = W1; B2T = B2T1; li = idx; N = 512; }
        else if (idx < 2 * 512 * 512) { W = W2; B2T = B2T2; li = idx - 512 * 512; N = 512; }
        else { W = W3; B2T = B2T3; li = idx - 2 * 512 * 512; N = 256; }
        int k = li / N, n = li % N;
        float v = W[(size_t)k * N + n];
        unsigned short hi = bf16_rn(v);
        unsigned short lo = bf16_rn(v - bf16_f32(hi));
        unsigned short* row = B2T + (size_t)n * KB;
        row[k] = hi;
        row[512 + k] = lo;
    }
}

// ---------------- x split (fp32 [N_NODES x 512] -> A2 [MPAD x KPHYS]) ----------------

__global__ __launch_bounds__(256) void split_x_kernel(const float* __restrict__ x,
                                                      unsigned short* __restrict__ A2) {
    int m = blockIdx.x;
    int ch = threadIdx.x * 2;
    unsigned short* arow = A2 + (size_t)m * KPHYS;
    float vx = 0.f, vy = 0.f;
    if (m < N_NODES) {
        float2 v = ntload2(x + (size_t)m * 512 + ch);  // x read exactly once
        vx = v.x;
        vy = v.y;
    }
    unsigned short hx = bf16_rn(vx), hy = bf16_rn(vy);
    arow[ch] = hx;
    arow[ch + 1] = hy;
    arow[512 + ch] = bf16_rn(vx - bf16_f32(hx));
    arow[512 + ch + 1] = bf16_rn(vy - bf16_f32(hy));
}

// ---------------- aggregation ----------------

__device__ __forceinline__ float gelu_tanh(float x) {
    float x3 = x * x * x;
    float inner = 0.7978845608028654f * (x + 0.044715f * x3);
    return 0.5f * x * (1.0f + tanhf(inner));
}

// One wave per node: 64 lanes x 8 fp16 ch = 512 ch. 4 nodes per 256-thread block.
// R8: streaming reads (CSR edge list, Chi/Clo self rows) are nontemporal so the
// 4MB per-XCD L2 is reserved for the gather rows (the only reused data).
__global__ __launch_bounds__(256) void aggregate_split_kernel(
    const __half* __restrict__ Chi, const __half* __restrict__ Clo,
    const int* __restrict__ offsets, const int2* __restrict__ csr_sw,
    const float* __restrict__ dinv,
    const float* __restrict__ bias, unsigned short* __restrict__ A2) {
    int t = threadIdx.x;
    int node = __builtin_amdgcn_readfirstlane(blockIdx.x * 4 + (t >> 6));
    int ch = (t & 63) * 8;
    unsigned short* arow = A2 + (size_t)node * KPHYS;
    if (node >= N_NODES) {  // zero pad rows (16B per store)
        *(uint4*)(arow + ch) = make_uint4(0, 0, 0, 0);
        *(uint4*)(arow + 512 + ch) = make_uint4(0, 0, 0, 0);
        return;
    }
    int p0 = offsets[node], p1 = offsets[node + 1];
    float a[8] = {0.f, 0.f, 0.f, 0.f, 0.f, 0.f, 0.f, 0.f};

    union H8 { float4 f4; f4v v4; __half2 h2[4]; };
    int p = p0;
    int pend8 = p0 + ((p1 - p0) & ~7);
    for (; p < pend8; p += 8) {
        int2 e[8];
#pragma unroll
        for (int j = 0; j < 8; j++) e[j] = ntload_edge(csr_sw + p + j);
        H8 v[8];
#pragma unroll
        for (int j = 0; j < 8; j++)
            v[j].f4 = *(const float4*)(Chi + (size_t)e[j].x * 512 + ch);
#pragma unroll
        for (int j = 0; j < 8; j++) {
            float wg = __int_as_float(e[j].y);
#pragma unroll
            for (int q = 0; q < 4; q++) {
                float2 c = __half22float2(v[j].h2[q]);
                a[2 * q] += wg * c.x;
                a[2 * q + 1] += wg * c.y;
            }
        }
    }
    if (p + 4 <= p1) {
        int2 e[4];
#pragma unroll
        for (int j = 0; j < 4; j++) e[j] = ntload_edge(csr_sw + p + j);
        H8 v[4];
#pragma unroll
        for (int j = 0; j < 4; j++)
            v[j].f4 = *(const float4*)(Chi + (size_t)e[j].x * 512 + ch);
#pragma unroll
        for (int j = 0; j < 4; j++) {
            float wg = __int_as_float(e[j].y);
#pragma unroll
            for (int q = 0; q < 4; q++) {
                float2 c = __half22float2(v[j].h2[q]);
                a[2 * q] += wg * c.x;
                a[2 * q + 1] += wg * c.y;
            }
        }
        p += 4;
    }
    for (; p < p1; p++) {
        int2 e = ntload_edge(csr_sw + p);
        float wg = __int_as_float(e.y);
        H8 v;
        v.f4 = *(const float4*)(Chi + (size_t)e.x * 512 + ch);
#pragma unroll
        for (int q = 0; q < 4; q++) {
            float2 c = __half22float2(v.h2[q]);
            a[2 * q] += wg * c.x;
            a[2 * q + 1] += wg * c.y;
        }
    }

    float di = dinv[node];
    float wself = di * di;
    H8 vh, vl;
    vh.v4 = ntload4f(Chi + (size_t)node * 512 + ch);  // self rows: read-once stream
    vl.v4 = ntload4f(Clo + (size_t)node * 512 + ch);
    float4 bv0 = *(const float4*)(bias + ch);
    float4 bv1 = *(const float4*)(bias + ch + 4);
    float s[8], b[8] = {bv0.x, bv0.y, bv0.z, bv0.w, bv1.x, bv1.y, bv1.z, bv1.w};
#pragma unroll
    for (int j = 0; j < 4; j++) {
        float2 ch2 = __half22float2(vh.h2[j]);
        float2 cl2 = __half22float2(vl.h2[j]);
        s[2 * j] = ch2.x + cl2.x;
        s[2 * j + 1] = ch2.y + cl2.y;
    }

    unsigned short hi[8], lo[8];
#pragma unroll
    for (int j = 0; j < 8; j++) {
        float v = gelu_tanh(a[j] + wself * s[j] + b[j]);
        hi[j] = bf16_rn(v);
        lo[j] = bf16_rn(v - bf16_f32(hi[j]));
    }
    *(ushort4*)(arow + ch) = make_ushort4(hi[0], hi[1], hi[2], hi[3]);
    *(ushort4*)(arow + ch + 4) = make_ushort4(hi[4], hi[5], hi[6], hi[7]);
    *(ushort4*)(arow + 512 + ch) = make_ushort4(lo[0], lo[1], lo[2], lo[3]);
    *(ushort4*)(arow + 512 + ch + 4) = make_ushort4(lo[4], lo[5], lo[6], lo[7]);
}

// Final agg: 256 ch, one wave per node (64 lanes x 4 fp16 ch), 4 nodes/block.
__global__ __launch_bounds__(256) void aggregate_final_kernel(
    const __half* __restrict__ Chi, const __half* __restrict__ Clo,
    const int* __restrict__ offsets, const int2* __restrict__ csr_sw,
    const float* __restrict__ dinv,
    const float* __restrict__ bias, float* __restrict__ out) {
    int t = threadIdx.x;
    int node = __builtin_amdgcn_readfirstlane(blockIdx.x * 4 + (t >> 6));
    if (node >= N_NODES) return;
    int ch = (t & 63) * 4;
    int p0 = offsets[node], p1 = offsets[node + 1];
    float ax = 0.f, ay = 0.f, az = 0.f, aw = 0.f;

    union H4 { float2 f2; f2v v2; __half2 h2[2]; };
    int p = p0;
    int pend8 = p0 + ((p1 - p0) & ~7);
    for (; p < pend8; p += 8) {
        int2 e[8];
#pragma unroll
        for (int j = 0; j < 8; j++) e[j] = ntload_edge(csr_sw + p + j);
        H4 v[8];
#pragma unroll
        for (int j = 0; j < 8; j++)
            v[j].f2 = *(const float2*)(Chi + (size_t)e[j].x * 256 + ch);
#pragma unroll
        for (int j = 0; j < 8; j++) {
            float wg = __int_as_float(e[j].y);
            float2 c0 = __half22float2(v[j].h2[0]), c1 = __half22float2(v[j].h2[1]);
            ax += wg * c0.x; ay += wg * c0.y; az += wg * c1.x; aw += wg * c1.y;
        }
    }
    for (; p < p1; p++) {
        int2 e = ntload_edge(csr_sw + p);
        float wg = __int_as_float(e.y);
        H4 v;
        v.f2 = *(const float2*)(Chi + (size_t)e.x * 256 + ch);
        float2 c0 = __half22float2(v.h2[0]), c1 = __half22float2(v.h2[1]);
        ax += wg * c0.x; ay += wg * c0.y; az += wg * c1.x; aw += wg * c1.y;
    }

    float di = dinv[node];
    float wself = di * di;
    H4 vh, vl;
    vh.v2 = __builtin_nontemporal_load((const f2v*)(Chi + (size_t)node * 256 + ch));
    vl.v2 = __builtin_nontemporal_load((const f2v*)(Clo + (size_t)node * 256 + ch));
    float2 h0 = __half22float2(vh.h2[0]), h1 = __half22float2(vh.h2[1]);
    float2 l0 = __half22float2(vl.h2[0]), l1 = __half22float2(vl.h2[1]);
    float4 bv = *(const float4*)(bias + ch);
    float4 o = make_float4(ax + wself * (h0.x + l0.x) + bv.x,
                           ay + wself * (h0.y + l0.y) + bv.y,
                           az + wself * (h1.x + l1.x) + bv.z,
                           aw + wself * (h1.y + l1.y) + bv.w);
    *(float4*)(out + (size_t)node * 256 + ch) = o;
}

// ---------------- launch ----------------

static inline char* align16(char* p) { return (char*)(((size_t)p + 15) & ~(size_t)15); }

extern "C" void kernel_launch(void* const* d_in, const int* in_sizes, int n_in,
                              void* d_out, int out_size, void* d_ws, size_t ws_size,
                              hipStream_t stream) {
    const float* x  = (const float*)d_in[0];
    const int* eidx = (const int*)d_in[1];
    const float* W1 = (const float*)d_in[2];
    const float* b1 = (const float*)d_in[3];
    const float* W2 = (const float*)d_in[4];
    const float* b2 = (const float*)d_in[5];
    const float* W3 = (const float*)d_in[6];
    const float* b3 = (const float*)d_in[7];
    float* out = (float*)d_out;

    const int* src = eidx;
    const int* dst = eidx + N_EDGES;

    char* ws = (char*)d_ws;
    unsigned short* A2 = (unsigned short*)ws;  ws += (size_t)MPAD * KPHYS * 2;   // 102.8 MB
    __half* Chi = (__half*)ws;                 ws += (size_t)MPAD * 512 * 2;      // 51.4 MB
    __half* Clo = (__half*)ws;                 ws += (size_t)MPAD * 512 * 2;      // 51.4 MB
    unsigned short* B2T1 = (unsigned short*)ws; ws += (size_t)512 * KB * 2;
    unsigned short* B2T2 = (unsigned short*)ws; ws += (size_t)512 * KB * 2;
    unsigned short* B2T3 = (unsigned short*)ws; ws += (size_t)256 * KB * 2;
    int* deg = (int*)ws;        ws = align16(ws + (size_t)N_NODES * 4);
    float* dinv = (float*)ws;   ws = align16(ws + (size_t)N_NODES * 4);
    int* offsets = (int*)ws;    ws = align16(ws + (size_t)(N_NODES + 1) * 4);
    int* cursor = (int*)ws;     ws = align16(ws + (size_t)N_NODES * 4);
    int2* csr_sw = (int2*)ws;   ws = align16(ws + (size_t)N_EDGES * 8);
    int* local_scan = (int*)ws; ws = align16(ws + (size_t)N_NODES * 4);
    int* partials = (int*)ws;   ws = align16(ws + (size_t)SCANB * 4);

    // ---- CSR build ----
    zero_int_kernel<<<(N_NODES + 255) / 256, 256, 0, stream>>>(deg, N_NODES);
    count_deg_kernel<<<(N_EDGES + 255) / 256, 256, 0, stream>>>(dst, deg);
    scan1_kernel<<<SCANB, 256, 0, stream>>>(deg, local_scan, partials);
    scan2_kernel<<<1, 256, 0, stream>>>(partials);
    scan3_kernel<<<SCANB, 256, 0, stream>>>(deg, local_scan, partials, offsets, cursor, dinv);
    fill_csr_kernel<<<(N_EDGES + 255) / 256, 256, 0, stream>>>(src, dst, cursor, csr_sw, dinv);

    // ---- weight + input splits ----
    wsplit_all_kernel<<<640, 256, 0, stream>>>(W1, B2T1, W2, B2T2, W3, B2T3);
    split_x_kernel<<<MPAD, 256, 0, stream>>>(x, A2);

    // XCD-affine GEMM grids: blocks = 8 * ceil(MT256/8) * ncol_tiles
    const int gemm_grid_512 = 8 * ((MT256 + 7) / 8) * 2;  // 400
    const int gemm_grid_256 = 8 * ((MT256 + 7) / 8) * 1;  // 200

    // ---- layer 1 ----
    {
        gemm_split_bt<<<gemm_grid_512, 512, 0, stream>>>(A2, B2T1, Chi, Clo, 512, 1);
        aggregate_split_kernel<<<MPAD / 4, 256, 0, stream>>>(Chi, Clo, offsets, csr_sw, dinv, b1, A2);
    }
    // ---- layer 2 ----
    {
        gemm_split_bt<<<gemm_grid_512, 512, 0, stream>>>(A2, B2T2, Chi, Clo, 512, 1);
        aggregate_split_kernel<<<MPAD / 4, 256, 0, stream>>>(Chi, Clo, offsets, csr_sw, dinv, b2, A2);
    }
    // ---- layer 3 ----
    {
        gemm_split_bt<<<gemm_grid_256, 512, 0, stream>>>(A2, B2T3, Chi, Clo, 256, 0);
        aggregate_final_kernel<<<MPAD / 4, 256, 0, stream>>>(Chi, Clo, offsets, csr_sw, dinv, b3, out);
    }
}